// Round 1
// baseline (2903.071 us; speedup 1.0000x reference)
//
#include <hip/hip_runtime.h>

#define D 128
#define BN_EPS 1e-5f

// ---------------------------------------------------------------------------
// Phase 1: agg[dst] += feat[src] * w    (edge-parallel, 32 threads/edge, f32
// atomics). Each thread handles 4 contiguous features via float4 gather.
// ---------------------------------------------------------------------------
__global__ __launch_bounds__(256) void scatter_kernel(
    const float* __restrict__ feat, const int* __restrict__ src,
    const int* __restrict__ dst, const float* __restrict__ ew,
    float* __restrict__ agg, int E)
{
    long tid = (long)blockIdx.x * blockDim.x + threadIdx.x;
    int e = (int)(tid >> 5);
    if (e >= E) return;
    int q = ((int)tid & 31) << 2;
    int s = src[e];
    int d = dst[e];
    float w = ew[e];
    float4 v = *reinterpret_cast<const float4*>(feat + (long)s * D + q);
    float* o = agg + (long)d * D + q;
    atomicAdd(o + 0, v.x * w);
    atomicAdd(o + 1, v.y * w);
    atomicAdd(o + 2, v.z * w);
    atomicAdd(o + 3, v.w * w);
}

// ---------------------------------------------------------------------------
// Phase 2: h = prelu(agg @ W + b, a1); write h to d_out; accumulate per-column
// sum and sum-of-squares into stats[0:128], stats[128:256].
// Block: 256 threads, 32 rows/block. Thread tile: 4 rows x 4 cols.
// W (64KB f32) staged in LDS once per block.
// ---------------------------------------------------------------------------
__global__ __launch_bounds__(256) void gemm_stats_kernel(
    const float* __restrict__ agg, const float* __restrict__ Wg,
    const float* __restrict__ bg, const float* __restrict__ a1,
    float* __restrict__ hout, float* __restrict__ stats, int N)
{
    __shared__ float Wl[D * D];          // 64 KB
    __shared__ float sblk[2][D];         // 1 KB

    int t = threadIdx.x;
    // cooperative load of W into LDS (4096 float4s / 256 threads = 16 each)
    for (int i = t; i < D * D / 4; i += 256) {
        reinterpret_cast<float4*>(Wl)[i] =
            reinterpret_cast<const float4*>(Wg)[i];
    }
    if (t < D) { sblk[0][t] = 0.f; sblk[1][t] = 0.f; }
    __syncthreads();

    const int cg = t & 31;       // column group (0..31)
    const int c0 = cg << 2;      // first of 4 columns
    const int rg = t >> 5;       // row group (0..7)
    const int rbase = blockIdx.x * 32 + rg * 4;

    const float a1v = a1[0];

    bool valid[4];
    #pragma unroll
    for (int i = 0; i < 4; ++i) valid[i] = (rbase + i) < N;

    float acc[4][4];
    float4 bv = *reinterpret_cast<const float4*>(bg + c0);
    #pragma unroll
    for (int i = 0; i < 4; ++i) {
        acc[i][0] = bv.x; acc[i][1] = bv.y; acc[i][2] = bv.z; acc[i][3] = bv.w;
    }

    for (int k0 = 0; k0 < D; k0 += 4) {
        float4 a[4];
        #pragma unroll
        for (int i = 0; i < 4; ++i) {
            a[i] = valid[i]
                ? *reinterpret_cast<const float4*>(agg + (long)(rbase + i) * D + k0)
                : make_float4(0.f, 0.f, 0.f, 0.f);
        }
        #pragma unroll
        for (int kk = 0; kk < 4; ++kk) {
            float4 wv = *reinterpret_cast<const float4*>(&Wl[(k0 + kk) * D + c0]);
            #pragma unroll
            for (int i = 0; i < 4; ++i) {
                float av = kk == 0 ? a[i].x : kk == 1 ? a[i].y : kk == 2 ? a[i].z : a[i].w;
                acc[i][0] += av * wv.x;
                acc[i][1] += av * wv.y;
                acc[i][2] += av * wv.z;
                acc[i][3] += av * wv.w;
            }
        }
    }

    // PReLU(a1), store h, accumulate column stats
    float csum[4] = {0.f, 0.f, 0.f, 0.f};
    float csq[4]  = {0.f, 0.f, 0.f, 0.f};
    #pragma unroll
    for (int i = 0; i < 4; ++i) {
        if (!valid[i]) continue;
        float4 o;
        #pragma unroll
        for (int j = 0; j < 4; ++j) {
            float v = acc[i][j];
            v = v >= 0.f ? v : v * a1v;
            (&o.x)[j] = v;
            csum[j] += v;
            csq[j]  += v * v;
        }
        *reinterpret_cast<float4*>(hout + (long)(rbase + i) * D + c0) = o;
    }
    #pragma unroll
    for (int j = 0; j < 4; ++j) {
        atomicAdd(&sblk[0][c0 + j], csum[j]);
        atomicAdd(&sblk[1][c0 + j], csq[j]);
    }
    __syncthreads();
    if (t < D) {
        atomicAdd(&stats[t],       sblk[0][t]);
        atomicAdd(&stats[D + t],   sblk[1][t]);
    }
}

// ---------------------------------------------------------------------------
// Phase 3: per-column scale/shift from batch stats (biased var, matches jnp.var)
// ---------------------------------------------------------------------------
__global__ void finalize_kernel(const float* __restrict__ stats,
                                const float* __restrict__ gamma,
                                const float* __restrict__ beta,
                                float* __restrict__ ss, int N)
{
    int c = threadIdx.x;
    float invN = 1.0f / (float)N;
    float mean = stats[c] * invN;
    float var  = stats[D + c] * invN - mean * mean;
    float sc = gamma[c] * rsqrtf(var + BN_EPS);
    ss[c]     = sc;
    ss[D + c] = beta[c] - mean * sc;
}

// ---------------------------------------------------------------------------
// Phase 4: out = prelu(h * scale + shift, a2)   (in place on d_out)
// ---------------------------------------------------------------------------
__global__ __launch_bounds__(256) void bn_prelu_kernel(
    float* __restrict__ h, const float* __restrict__ ss,
    const float* __restrict__ a2, long n4)
{
    const float a2v = a2[0];
    long i = (long)blockIdx.x * blockDim.x + threadIdx.x;
    long stride = (long)gridDim.x * blockDim.x;
    for (; i < n4; i += stride) {
        float4 x = reinterpret_cast<float4*>(h)[i];
        int c0 = ((int)(i & 31)) << 2;   // D/4 = 32 groups per row
        float4 sc = *reinterpret_cast<const float4*>(ss + c0);
        float4 sh = *reinterpret_cast<const float4*>(ss + D + c0);
        float v;
        v = x.x * sc.x + sh.x; x.x = v >= 0.f ? v : v * a2v;
        v = x.y * sc.y + sh.y; x.y = v >= 0.f ? v : v * a2v;
        v = x.z * sc.z + sh.z; x.z = v >= 0.f ? v : v * a2v;
        v = x.w * sc.w + sh.w; x.w = v >= 0.f ? v : v * a2v;
        reinterpret_cast<float4*>(h)[i] = x;
    }
}

// ---------------------------------------------------------------------------
extern "C" void kernel_launch(void* const* d_in, const int* in_sizes, int n_in,
                              void* d_out, int out_size, void* d_ws, size_t ws_size,
                              hipStream_t stream)
{
    const float* feat  = (const float*)d_in[0];
    const int*   src   = (const int*)d_in[1];
    const int*   dst   = (const int*)d_in[2];
    const float* ew    = (const float*)d_in[3];
    const float* W     = (const float*)d_in[4];
    const float* b     = (const float*)d_in[5];
    const float* a1    = (const float*)d_in[6];
    const float* gamma = (const float*)d_in[7];
    const float* beta  = (const float*)d_in[8];
    const float* a2    = (const float*)d_in[9];

    const int N = in_sizes[0] / D;
    const int E = in_sizes[1];

    float* agg   = (float*)d_ws;                 // N*D floats
    float* stats = agg + (size_t)N * D;          // 256 floats (sum, sumsq)
    float* ss    = stats + 2 * D;                // 256 floats (scale, shift)
    float* out   = (float*)d_out;

    // zero agg + stats every call (deterministic across graph replays)
    hipMemsetAsync(agg, 0, ((size_t)N * D + 2 * D) * sizeof(float), stream);

    // Phase 1: scatter-aggregate
    long nthreads = (long)E * 32;
    int sblocks = (int)((nthreads + 255) / 256);
    scatter_kernel<<<sblocks, 256, 0, stream>>>(feat, src, dst, ew, agg, E);

    // Phase 2: GEMM + bias + PReLU(a1) + column stats
    int gblocks = (N + 31) / 32;
    gemm_stats_kernel<<<gblocks, 256, 0, stream>>>(agg, W, b, a1, out, stats, N);

    // Phase 3: BN scale/shift
    finalize_kernel<<<1, D, 0, stream>>>(stats, gamma, beta, ss, N);

    // Phase 4: BN apply + PReLU(a2), in place on d_out
    long n4 = (long)N * D / 4;
    bn_prelu_kernel<<<2048, 256, 0, stream>>>(out, ss, a2, n4);
}

// Round 2
// 767.919 us; speedup vs baseline: 3.7804x; 3.7804x over previous
//
#include <hip/hip_runtime.h>

#define D 128
#define BN_EPS 1e-5f

// ===========================================================================
// CSR-by-dst build: histogram -> exclusive scan -> reorder (packed {src,w})
// ===========================================================================

__global__ __launch_bounds__(256) void hist_kernel(
    const int* __restrict__ dst, int* __restrict__ deg, int E)
{
    int i = blockIdx.x * 256 + threadIdx.x;
    int stride = gridDim.x * 256;
    for (; i < E; i += stride) atomicAdd(&deg[dst[i]], 1);
}

// Single-block exclusive scan over N degrees. Writes off[0..N] and resets
// deg[i] to the exclusive prefix (deg doubles as the reorder cursor).
__global__ __launch_bounds__(1024) void scan_kernel(
    int* __restrict__ deg, int* __restrict__ off, int N, int E)
{
    __shared__ int part[1024];
    int t = threadIdx.x;
    int chunk = (N + 1023) / 1024;
    int lo = t * chunk;
    int hi = lo + chunk; if (hi > N) hi = N;
    int s = 0;
    for (int i = lo; i < hi; ++i) s += deg[i];
    part[t] = s;
    __syncthreads();
    for (int d = 1; d < 1024; d <<= 1) {
        int v = (t >= d) ? part[t - d] : 0;
        __syncthreads();
        part[t] += v;
        __syncthreads();
    }
    int run = part[t] - s;               // exclusive prefix of this chunk
    for (int i = lo; i < hi; ++i) {
        int dv = deg[i];
        off[i] = run;
        deg[i] = run;                    // becomes cursor
        run += dv;
    }
    if (t == 1023) off[N] = E;
}

__global__ __launch_bounds__(256) void reorder_kernel(
    const int* __restrict__ src, const int* __restrict__ dst,
    const float* __restrict__ ew, int* __restrict__ cursor,
    int2* __restrict__ csr, int E)
{
    int i = blockIdx.x * 256 + threadIdx.x;
    int stride = gridDim.x * 256;
    for (; i < E; i += stride) {
        int p = atomicAdd(&cursor[dst[i]], 1);
        csr[p] = make_int2(src[i], __float_as_int(ew[i]));
    }
}

// ===========================================================================
// Atomic-free aggregation: 32 lanes per node, float4 per lane, register acc.
// ===========================================================================
__global__ __launch_bounds__(256) void gather_agg_kernel(
    const float* __restrict__ feat, const int2* __restrict__ csr,
    const int* __restrict__ off, float* __restrict__ agg, int N)
{
    int g = (int)((blockIdx.x * 256 + threadIdx.x) >> 5);
    if (g >= N) return;
    int q = (threadIdx.x & 31) << 2;
    int beg = off[g], end = off[g + 1];
    float4 acc = make_float4(0.f, 0.f, 0.f, 0.f);
    int i = beg;
    for (; i + 2 <= end; i += 2) {
        int2 e0 = csr[i];
        int2 e1 = csr[i + 1];
        const float4 v0 = *reinterpret_cast<const float4*>(feat + (long)e0.x * D + q);
        const float4 v1 = *reinterpret_cast<const float4*>(feat + (long)e1.x * D + q);
        float w0 = __int_as_float(e0.y), w1 = __int_as_float(e1.y);
        acc.x += v0.x * w0; acc.y += v0.y * w0; acc.z += v0.z * w0; acc.w += v0.w * w0;
        acc.x += v1.x * w1; acc.y += v1.y * w1; acc.z += v1.z * w1; acc.w += v1.w * w1;
    }
    if (i < end) {
        int2 e0 = csr[i];
        const float4 v0 = *reinterpret_cast<const float4*>(feat + (long)e0.x * D + q);
        float w0 = __int_as_float(e0.y);
        acc.x += v0.x * w0; acc.y += v0.y * w0; acc.z += v0.z * w0; acc.w += v0.w * w0;
    }
    *reinterpret_cast<float4*>(agg + (long)g * D + q) = acc;
}

// ===========================================================================
// Fallback (ws too small for CSR): edge-parallel atomic scatter.
// ===========================================================================
__global__ __launch_bounds__(256) void scatter_kernel(
    const float* __restrict__ feat, const int* __restrict__ src,
    const int* __restrict__ dst, const float* __restrict__ ew,
    float* __restrict__ agg, int E)
{
    long tid = (long)blockIdx.x * blockDim.x + threadIdx.x;
    int e = (int)(tid >> 5);
    if (e >= E) return;
    int q = ((int)tid & 31) << 2;
    int s = src[e];
    int d = dst[e];
    float w = ew[e];
    float4 v = *reinterpret_cast<const float4*>(feat + (long)s * D + q);
    float* o = agg + (long)d * D + q;
    atomicAdd(o + 0, v.x * w);
    atomicAdd(o + 1, v.y * w);
    atomicAdd(o + 2, v.z * w);
    atomicAdd(o + 3, v.w * w);
}

// ===========================================================================
// Phase 2: h = prelu(agg @ W + b, a1); store h; per-column sum/sumsq stats.
// ===========================================================================
__global__ __launch_bounds__(256) void gemm_stats_kernel(
    const float* __restrict__ agg, const float* __restrict__ Wg,
    const float* __restrict__ bg, const float* __restrict__ a1,
    float* __restrict__ hout, float* __restrict__ stats, int N)
{
    __shared__ float Wl[D * D];          // 64 KB
    __shared__ float sblk[2][D];

    int t = threadIdx.x;
    for (int i = t; i < D * D / 4; i += 256) {
        reinterpret_cast<float4*>(Wl)[i] =
            reinterpret_cast<const float4*>(Wg)[i];
    }
    if (t < D) { sblk[0][t] = 0.f; sblk[1][t] = 0.f; }
    __syncthreads();

    const int c0 = (t & 31) << 2;
    const int rbase = blockIdx.x * 32 + (t >> 5) * 4;
    const float a1v = a1[0];

    bool valid[4];
    #pragma unroll
    for (int i = 0; i < 4; ++i) valid[i] = (rbase + i) < N;

    float acc[4][4];
    float4 bv = *reinterpret_cast<const float4*>(bg + c0);
    #pragma unroll
    for (int i = 0; i < 4; ++i) {
        acc[i][0] = bv.x; acc[i][1] = bv.y; acc[i][2] = bv.z; acc[i][3] = bv.w;
    }

    for (int k0 = 0; k0 < D; k0 += 4) {
        float4 a[4];
        #pragma unroll
        for (int i = 0; i < 4; ++i) {
            a[i] = valid[i]
                ? *reinterpret_cast<const float4*>(agg + (long)(rbase + i) * D + k0)
                : make_float4(0.f, 0.f, 0.f, 0.f);
        }
        #pragma unroll
        for (int kk = 0; kk < 4; ++kk) {
            float4 wv = *reinterpret_cast<const float4*>(&Wl[(k0 + kk) * D + c0]);
            #pragma unroll
            for (int i = 0; i < 4; ++i) {
                float av = kk == 0 ? a[i].x : kk == 1 ? a[i].y : kk == 2 ? a[i].z : a[i].w;
                acc[i][0] += av * wv.x;
                acc[i][1] += av * wv.y;
                acc[i][2] += av * wv.z;
                acc[i][3] += av * wv.w;
            }
        }
    }

    float csum[4] = {0.f, 0.f, 0.f, 0.f};
    float csq[4]  = {0.f, 0.f, 0.f, 0.f};
    #pragma unroll
    for (int i = 0; i < 4; ++i) {
        if (!valid[i]) continue;
        float4 o;
        #pragma unroll
        for (int j = 0; j < 4; ++j) {
            float v = acc[i][j];
            v = v >= 0.f ? v : v * a1v;
            (&o.x)[j] = v;
            csum[j] += v;
            csq[j]  += v * v;
        }
        *reinterpret_cast<float4*>(hout + (long)(rbase + i) * D + c0) = o;
    }
    #pragma unroll
    for (int j = 0; j < 4; ++j) {
        atomicAdd(&sblk[0][c0 + j], csum[j]);
        atomicAdd(&sblk[1][c0 + j], csq[j]);
    }
    __syncthreads();
    if (t < D) {
        atomicAdd(&stats[t],     sblk[0][t]);
        atomicAdd(&stats[D + t], sblk[1][t]);
    }
}

__global__ void finalize_kernel(const float* __restrict__ stats,
                                const float* __restrict__ gamma,
                                const float* __restrict__ beta,
                                float* __restrict__ ss, int N)
{
    int c = threadIdx.x;
    float invN = 1.0f / (float)N;
    float mean = stats[c] * invN;
    float var  = stats[D + c] * invN - mean * mean;
    float sc = gamma[c] * rsqrtf(var + BN_EPS);
    ss[c]     = sc;
    ss[D + c] = beta[c] - mean * sc;
}

__global__ __launch_bounds__(256) void bn_prelu_kernel(
    float* __restrict__ h, const float* __restrict__ ss,
    const float* __restrict__ a2, long n4)
{
    const float a2v = a2[0];
    long i = (long)blockIdx.x * blockDim.x + threadIdx.x;
    long stride = (long)gridDim.x * blockDim.x;
    for (; i < n4; i += stride) {
        float4 x = reinterpret_cast<float4*>(h)[i];
        int c0 = ((int)(i & 31)) << 2;
        float4 sc = *reinterpret_cast<const float4*>(ss + c0);
        float4 sh = *reinterpret_cast<const float4*>(ss + D + c0);
        float v;
        v = x.x * sc.x + sh.x; x.x = v >= 0.f ? v : v * a2v;
        v = x.y * sc.y + sh.y; x.y = v >= 0.f ? v : v * a2v;
        v = x.z * sc.z + sh.z; x.z = v >= 0.f ? v : v * a2v;
        v = x.w * sc.w + sh.w; x.w = v >= 0.f ? v : v * a2v;
        reinterpret_cast<float4*>(h)[i] = x;
    }
}

// ===========================================================================
extern "C" void kernel_launch(void* const* d_in, const int* in_sizes, int n_in,
                              void* d_out, int out_size, void* d_ws, size_t ws_size,
                              hipStream_t stream)
{
    const float* feat  = (const float*)d_in[0];
    const int*   src   = (const int*)d_in[1];
    const int*   dst   = (const int*)d_in[2];
    const float* ew    = (const float*)d_in[3];
    const float* W     = (const float*)d_in[4];
    const float* b     = (const float*)d_in[5];
    const float* a1    = (const float*)d_in[6];
    const float* gamma = (const float*)d_in[7];
    const float* beta  = (const float*)d_in[8];
    const float* a2    = (const float*)d_in[9];

    const int N = in_sizes[0] / D;
    const int E = in_sizes[1];

    // ws layout
    char* p = (char*)d_ws;
    float* agg = (float*)p;               p += (size_t)N * D * sizeof(float);
    int2*  csr = (int2*)p;                p += (size_t)E * sizeof(int2);
    int*   deg = (int*)p;                 p += (size_t)N * sizeof(int);   // also cursor
    int*   off = (int*)p;                 p += (size_t)(N + 1) * sizeof(int);
    float* stats = (float*)p;             p += 2 * D * sizeof(float);
    float* ss    = (float*)p;             p += 2 * D * sizeof(float);
    size_t need = (size_t)(p - (char*)d_ws);
    float* out = (float*)d_out;

    if (ws_size >= need) {
        // ---- CSR path ----
        hipMemsetAsync(deg, 0, (size_t)N * sizeof(int), stream);
        hipMemsetAsync(stats, 0, 2 * D * sizeof(float), stream);
        hist_kernel<<<2048, 256, 0, stream>>>(dst, deg, E);
        scan_kernel<<<1, 1024, 0, stream>>>(deg, off, N, E);
        reorder_kernel<<<2048, 256, 0, stream>>>(src, dst, ew, deg, csr, E);
        int ablocks = (int)(((long)N * 32 + 255) / 256);
        gather_agg_kernel<<<ablocks, 256, 0, stream>>>(feat, csr, off, agg, N);
    } else {
        // ---- fallback: atomic scatter ----
        stats = agg + (size_t)N * D;
        ss    = stats + 2 * D;
        hipMemsetAsync(agg, 0, ((size_t)N * D + 2 * D) * sizeof(float), stream);
        long nthreads = (long)E * 32;
        int sblocks = (int)((nthreads + 255) / 256);
        scatter_kernel<<<sblocks, 256, 0, stream>>>(feat, src, dst, ew, agg, E);
    }

    int gblocks = (N + 31) / 32;
    gemm_stats_kernel<<<gblocks, 256, 0, stream>>>(agg, W, b, a1, out, stats, N);
    finalize_kernel<<<1, D, 0, stream>>>(stats, gamma, beta, ss, N);
    long n4 = (long)N * D / 4;
    bn_prelu_kernel<<<2048, 256, 0, stream>>>(out, ss, a2, n4);
}

// Round 3
// 556.991 us; speedup vs baseline: 5.2121x; 1.3787x over previous
//
#include <hip/hip_runtime.h>

#define D 128
#define BN_EPS 1e-5f

// ===========================================================================
// CSR-by-dst build: histogram -> hierarchical scan -> reorder (packed {src,w})
// ===========================================================================

__global__ __launch_bounds__(256) void hist_kernel(
    const int* __restrict__ dst, int* __restrict__ deg, int E)
{
    int i = blockIdx.x * 256 + threadIdx.x;
    int stride = gridDim.x * 256;
    for (; i < E; i += stride) atomicAdd(&deg[dst[i]], 1);
}

// Level 1: each block scans 1024 degrees (256 threads x int4), writes
// within-block exclusive prefixes to off[] and the block total to bsum[].
__global__ __launch_bounds__(256) void scan_block_kernel(
    const int* __restrict__ deg, int* __restrict__ off,
    int* __restrict__ bsum, int N)
{
    __shared__ int lsum[256];
    int t = threadIdx.x;
    int base = blockIdx.x * 1024 + t * 4;
    int4 v = make_int4(0, 0, 0, 0);
    if (base + 3 < N) {
        v = *reinterpret_cast<const int4*>(deg + base);
    } else {
        if (base + 0 < N) v.x = deg[base + 0];
        if (base + 1 < N) v.y = deg[base + 1];
        if (base + 2 < N) v.z = deg[base + 2];
        if (base + 3 < N) v.w = deg[base + 3];
    }
    int s = v.x + v.y + v.z + v.w;
    lsum[t] = s;
    __syncthreads();
    for (int d = 1; d < 256; d <<= 1) {
        int val = (t >= d) ? lsum[t - d] : 0;
        __syncthreads();
        lsum[t] += val;
        __syncthreads();
    }
    int run = lsum[t] - s;               // exclusive prefix within block
    if (t == 255) bsum[blockIdx.x] = lsum[t];
    if (base + 0 < N) { off[base + 0] = run; run += v.x; }
    if (base + 1 < N) { off[base + 1] = run; run += v.y; }
    if (base + 2 < N) { off[base + 2] = run; run += v.z; }
    if (base + 3 < N) { off[base + 3] = run; run += v.w; }
}

// Level 2: single-block exclusive scan of the (<=1024) block totals.
__global__ __launch_bounds__(1024) void scan_bsum_kernel(int* bsum, int nb)
{
    __shared__ int l[1024];
    int t = threadIdx.x;
    int v = (t < nb) ? bsum[t] : 0;
    l[t] = v;
    __syncthreads();
    for (int d = 1; d < 1024; d <<= 1) {
        int val = (t >= d) ? l[t - d] : 0;
        __syncthreads();
        l[t] += val;
        __syncthreads();
    }
    if (t < nb) bsum[t] = l[t] - v;      // exclusive
}

// Level 3: add block offsets; off[] final; cursor[] initialized for reorder.
__global__ __launch_bounds__(256) void add_off_kernel(
    int* __restrict__ off, const int* __restrict__ bsum,
    int* __restrict__ cursor, int N, int E)
{
    int bo = bsum[blockIdx.x];
    int base = blockIdx.x * 1024 + threadIdx.x * 4;
    #pragma unroll
    for (int j = 0; j < 4; ++j) {
        int i = base + j;
        if (i < N) { int o = off[i] + bo; off[i] = o; cursor[i] = o; }
    }
    if (blockIdx.x == 0 && threadIdx.x == 0) off[N] = E;
}

__global__ __launch_bounds__(256) void reorder_kernel(
    const int* __restrict__ src, const int* __restrict__ dst,
    const float* __restrict__ ew, int* __restrict__ cursor,
    int2* __restrict__ csr, int E)
{
    int i = blockIdx.x * 256 + threadIdx.x;
    int stride = gridDim.x * 256;
    for (; i < E; i += stride) {
        int p = atomicAdd(&cursor[dst[i]], 1);
        csr[p] = make_int2(src[i], __float_as_int(ew[i]));
    }
}

// ===========================================================================
// Atomic-free aggregation: 32 lanes per node, float4 per lane, register acc.
// ===========================================================================
__global__ __launch_bounds__(256) void gather_agg_kernel(
    const float* __restrict__ feat, const int2* __restrict__ csr,
    const int* __restrict__ off, float* __restrict__ agg, int N)
{
    int g = (int)((blockIdx.x * 256 + threadIdx.x) >> 5);
    if (g >= N) return;
    int q = (threadIdx.x & 31) << 2;
    int beg = off[g], end = off[g + 1];
    float4 acc = make_float4(0.f, 0.f, 0.f, 0.f);
    int i = beg;
    for (; i + 2 <= end; i += 2) {
        int2 e0 = csr[i];
        int2 e1 = csr[i + 1];
        const float4 v0 = *reinterpret_cast<const float4*>(feat + (long)e0.x * D + q);
        const float4 v1 = *reinterpret_cast<const float4*>(feat + (long)e1.x * D + q);
        float w0 = __int_as_float(e0.y), w1 = __int_as_float(e1.y);
        acc.x += v0.x * w0; acc.y += v0.y * w0; acc.z += v0.z * w0; acc.w += v0.w * w0;
        acc.x += v1.x * w1; acc.y += v1.y * w1; acc.z += v1.z * w1; acc.w += v1.w * w1;
    }
    if (i < end) {
        int2 e0 = csr[i];
        const float4 v0 = *reinterpret_cast<const float4*>(feat + (long)e0.x * D + q);
        float w0 = __int_as_float(e0.y);
        acc.x += v0.x * w0; acc.y += v0.y * w0; acc.z += v0.z * w0; acc.w += v0.w * w0;
    }
    *reinterpret_cast<float4*>(agg + (long)g * D + q) = acc;
}

// ===========================================================================
// Fallback (ws too small for CSR): edge-parallel atomic scatter.
// ===========================================================================
__global__ __launch_bounds__(256) void scatter_kernel(
    const float* __restrict__ feat, const int* __restrict__ src,
    const int* __restrict__ dst, const float* __restrict__ ew,
    float* __restrict__ agg, int E)
{
    long tid = (long)blockIdx.x * blockDim.x + threadIdx.x;
    int e = (int)(tid >> 5);
    if (e >= E) return;
    int q = ((int)tid & 31) << 2;
    int s = src[e];
    int d = dst[e];
    float w = ew[e];
    float4 v = *reinterpret_cast<const float4*>(feat + (long)s * D + q);
    float* o = agg + (long)d * D + q;
    atomicAdd(o + 0, v.x * w);
    atomicAdd(o + 1, v.y * w);
    atomicAdd(o + 2, v.z * w);
    atomicAdd(o + 3, v.w * w);
}

// ===========================================================================
// Phase 2: h = prelu(agg @ W + b, a1); store h; per-column sum/sumsq stats.
// ===========================================================================
__global__ __launch_bounds__(256) void gemm_stats_kernel(
    const float* __restrict__ agg, const float* __restrict__ Wg,
    const float* __restrict__ bg, const float* __restrict__ a1,
    float* __restrict__ hout, float* __restrict__ stats, int N)
{
    __shared__ float Wl[D * D];          // 64 KB
    __shared__ float sblk[2][D];

    int t = threadIdx.x;
    for (int i = t; i < D * D / 4; i += 256) {
        reinterpret_cast<float4*>(Wl)[i] =
            reinterpret_cast<const float4*>(Wg)[i];
    }
    if (t < D) { sblk[0][t] = 0.f; sblk[1][t] = 0.f; }
    __syncthreads();

    const int c0 = (t & 31) << 2;
    const int rbase = blockIdx.x * 32 + (t >> 5) * 4;
    const float a1v = a1[0];

    bool valid[4];
    #pragma unroll
    for (int i = 0; i < 4; ++i) valid[i] = (rbase + i) < N;

    float acc[4][4];
    float4 bv = *reinterpret_cast<const float4*>(bg + c0);
    #pragma unroll
    for (int i = 0; i < 4; ++i) {
        acc[i][0] = bv.x; acc[i][1] = bv.y; acc[i][2] = bv.z; acc[i][3] = bv.w;
    }

    for (int k0 = 0; k0 < D; k0 += 4) {
        float4 a[4];
        #pragma unroll
        for (int i = 0; i < 4; ++i) {
            a[i] = valid[i]
                ? *reinterpret_cast<const float4*>(agg + (long)(rbase + i) * D + k0)
                : make_float4(0.f, 0.f, 0.f, 0.f);
        }
        #pragma unroll
        for (int kk = 0; kk < 4; ++kk) {
            float4 wv = *reinterpret_cast<const float4*>(&Wl[(k0 + kk) * D + c0]);
            #pragma unroll
            for (int i = 0; i < 4; ++i) {
                float av = kk == 0 ? a[i].x : kk == 1 ? a[i].y : kk == 2 ? a[i].z : a[i].w;
                acc[i][0] += av * wv.x;
                acc[i][1] += av * wv.y;
                acc[i][2] += av * wv.z;
                acc[i][3] += av * wv.w;
            }
        }
    }

    float csum[4] = {0.f, 0.f, 0.f, 0.f};
    float csq[4]  = {0.f, 0.f, 0.f, 0.f};
    #pragma unroll
    for (int i = 0; i < 4; ++i) {
        if (!valid[i]) continue;
        float4 o;
        #pragma unroll
        for (int j = 0; j < 4; ++j) {
            float v = acc[i][j];
            v = v >= 0.f ? v : v * a1v;
            (&o.x)[j] = v;
            csum[j] += v;
            csq[j]  += v * v;
        }
        *reinterpret_cast<float4*>(hout + (long)(rbase + i) * D + c0) = o;
    }
    #pragma unroll
    for (int j = 0; j < 4; ++j) {
        atomicAdd(&sblk[0][c0 + j], csum[j]);
        atomicAdd(&sblk[1][c0 + j], csq[j]);
    }
    __syncthreads();
    if (t < D) {
        atomicAdd(&stats[t],     sblk[0][t]);
        atomicAdd(&stats[D + t], sblk[1][t]);
    }
}

__global__ void finalize_kernel(const float* __restrict__ stats,
                                const float* __restrict__ gamma,
                                const float* __restrict__ beta,
                                float* __restrict__ ss, int N)
{
    int c = threadIdx.x;
    float invN = 1.0f / (float)N;
    float mean = stats[c] * invN;
    float var  = stats[D + c] * invN - mean * mean;
    float sc = gamma[c] * rsqrtf(var + BN_EPS);
    ss[c]     = sc;
    ss[D + c] = beta[c] - mean * sc;
}

__global__ __launch_bounds__(256) void bn_prelu_kernel(
    float* __restrict__ h, const float* __restrict__ ss,
    const float* __restrict__ a2, long n4)
{
    const float a2v = a2[0];
    long i = (long)blockIdx.x * blockDim.x + threadIdx.x;
    long stride = (long)gridDim.x * blockDim.x;
    for (; i < n4; i += stride) {
        float4 x = reinterpret_cast<float4*>(h)[i];
        int c0 = ((int)(i & 31)) << 2;
        float4 sc = *reinterpret_cast<const float4*>(ss + c0);
        float4 sh = *reinterpret_cast<const float4*>(ss + D + c0);
        float v;
        v = x.x * sc.x + sh.x; x.x = v >= 0.f ? v : v * a2v;
        v = x.y * sc.y + sh.y; x.y = v >= 0.f ? v : v * a2v;
        v = x.z * sc.z + sh.z; x.z = v >= 0.f ? v : v * a2v;
        v = x.w * sc.w + sh.w; x.w = v >= 0.f ? v : v * a2v;
        reinterpret_cast<float4*>(h)[i] = x;
    }
}

// ===========================================================================
extern "C" void kernel_launch(void* const* d_in, const int* in_sizes, int n_in,
                              void* d_out, int out_size, void* d_ws, size_t ws_size,
                              hipStream_t stream)
{
    const float* feat  = (const float*)d_in[0];
    const int*   src   = (const int*)d_in[1];
    const int*   dst   = (const int*)d_in[2];
    const float* ew    = (const float*)d_in[3];
    const float* W     = (const float*)d_in[4];
    const float* b     = (const float*)d_in[5];
    const float* a1    = (const float*)d_in[6];
    const float* gamma = (const float*)d_in[7];
    const float* beta  = (const float*)d_in[8];
    const float* a2    = (const float*)d_in[9];

    const int N = in_sizes[0] / D;
    const int E = in_sizes[1];

    // ws layout (all chunks 16B-aligned)
    char* p = (char*)d_ws;
    float* agg = (float*)p;               p += (size_t)N * D * sizeof(float);
    int2*  csr = (int2*)p;                p += (size_t)E * sizeof(int2);
    int*   deg = (int*)p;                 p += (size_t)((N + 3) & ~3) * sizeof(int);   // cursor
    int*   off = (int*)p;                 p += (size_t)((N + 5) & ~3) * sizeof(int);
    int*   bsum = (int*)p;                p += 1024 * sizeof(int);
    float* stats = (float*)p;             p += 2 * D * sizeof(float);
    float* ss    = (float*)p;             p += 2 * D * sizeof(float);
    size_t need = (size_t)(p - (char*)d_ws);
    float* out = (float*)d_out;

    int nb = (N + 1023) / 1024;           // scan blocks (N <= ~1M supported)

    if (ws_size >= need && nb <= 1024) {
        // ---- CSR path ----
        hipMemsetAsync(deg, 0, (size_t)N * sizeof(int), stream);
        hipMemsetAsync(stats, 0, 2 * D * sizeof(float), stream);
        hist_kernel<<<2048, 256, 0, stream>>>(dst, deg, E);
        scan_block_kernel<<<nb, 256, 0, stream>>>(deg, off, bsum, N);
        scan_bsum_kernel<<<1, 1024, 0, stream>>>(bsum, nb);
        add_off_kernel<<<nb, 256, 0, stream>>>(off, bsum, deg, N, E);
        reorder_kernel<<<2048, 256, 0, stream>>>(src, dst, ew, deg, csr, E);
        int ablocks = (int)(((long)N * 32 + 255) / 256);
        gather_agg_kernel<<<ablocks, 256, 0, stream>>>(feat, csr, off, agg, N);
    } else {
        // ---- fallback: atomic scatter ----
        stats = agg + (size_t)N * D;
        ss    = stats + 2 * D;
        hipMemsetAsync(agg, 0, ((size_t)N * D + 2 * D) * sizeof(float), stream);
        long nthreads = (long)E * 32;
        int sblocks = (int)((nthreads + 255) / 256);
        scatter_kernel<<<sblocks, 256, 0, stream>>>(feat, src, dst, ew, agg, E);
    }

    int gblocks = (N + 31) / 32;
    gemm_stats_kernel<<<gblocks, 256, 0, stream>>>(agg, W, b, a1, out, stats, N);
    finalize_kernel<<<1, D, 0, stream>>>(stats, gamma, beta, ss, N);
    long n4 = (long)N * D / 4;
    bn_prelu_kernel<<<2048, 256, 0, stream>>>(out, ss, a2, n4);
}

// Round 4
// 383.061 us; speedup vs baseline: 7.5786x; 1.4541x over previous
//
#include <hip/hip_runtime.h>

#define D 128
#define BN_EPS 1e-5f

typedef __attribute__((ext_vector_type(8))) short bf16x8;
typedef __attribute__((ext_vector_type(4))) float f32x4;

__device__ __forceinline__ unsigned short f2bf(float f) {
    unsigned int u = __float_as_uint(f);
    u += 0x7FFFu + ((u >> 16) & 1u);
    return (unsigned short)(u >> 16);
}

// ===========================================================================
// CSR-by-dst build: histogram -> hierarchical scan -> reorder (packed {src,w})
// ===========================================================================

__global__ __launch_bounds__(256) void hist_kernel(
    const int* __restrict__ dst, int* __restrict__ deg, int E)
{
    int i = blockIdx.x * 256 + threadIdx.x;
    int stride = gridDim.x * 256;
    for (; i < E; i += stride) atomicAdd(&deg[dst[i]], 1);
}

__global__ __launch_bounds__(256) void scan_block_kernel(
    const int* __restrict__ deg, int* __restrict__ off,
    int* __restrict__ bsum, int N)
{
    __shared__ int lsum[256];
    int t = threadIdx.x;
    int base = blockIdx.x * 1024 + t * 4;
    int4 v = make_int4(0, 0, 0, 0);
    if (base + 3 < N) {
        v = *reinterpret_cast<const int4*>(deg + base);
    } else {
        if (base + 0 < N) v.x = deg[base + 0];
        if (base + 1 < N) v.y = deg[base + 1];
        if (base + 2 < N) v.z = deg[base + 2];
        if (base + 3 < N) v.w = deg[base + 3];
    }
    int s = v.x + v.y + v.z + v.w;
    lsum[t] = s;
    __syncthreads();
    for (int d = 1; d < 256; d <<= 1) {
        int val = (t >= d) ? lsum[t - d] : 0;
        __syncthreads();
        lsum[t] += val;
        __syncthreads();
    }
    int run = lsum[t] - s;
    if (t == 255) bsum[blockIdx.x] = lsum[t];
    if (base + 0 < N) { off[base + 0] = run; run += v.x; }
    if (base + 1 < N) { off[base + 1] = run; run += v.y; }
    if (base + 2 < N) { off[base + 2] = run; run += v.z; }
    if (base + 3 < N) { off[base + 3] = run; run += v.w; }
}

__global__ __launch_bounds__(1024) void scan_bsum_kernel(int* bsum, int nb)
{
    __shared__ int l[1024];
    int t = threadIdx.x;
    int v = (t < nb) ? bsum[t] : 0;
    l[t] = v;
    __syncthreads();
    for (int d = 1; d < 1024; d <<= 1) {
        int val = (t >= d) ? l[t - d] : 0;
        __syncthreads();
        l[t] += val;
        __syncthreads();
    }
    if (t < nb) bsum[t] = l[t] - v;
}

__global__ __launch_bounds__(256) void add_off_kernel(
    int* __restrict__ off, const int* __restrict__ bsum,
    int* __restrict__ cursor, int N, int E)
{
    int bo = bsum[blockIdx.x];
    int base = blockIdx.x * 1024 + threadIdx.x * 4;
    #pragma unroll
    for (int j = 0; j < 4; ++j) {
        int i = base + j;
        if (i < N) { int o = off[i] + bo; off[i] = o; cursor[i] = o; }
    }
    if (blockIdx.x == 0 && threadIdx.x == 0) off[N] = E;
}

__global__ __launch_bounds__(256) void reorder_kernel(
    const int* __restrict__ src, const int* __restrict__ dst,
    const float* __restrict__ ew, int* __restrict__ cursor,
    int2* __restrict__ csr, int E)
{
    int i = blockIdx.x * 256 + threadIdx.x;
    int stride = gridDim.x * 256;
    for (; i < E; i += stride) {
        int p = atomicAdd(&cursor[dst[i]], 1);
        csr[p] = make_int2(src[i], __float_as_int(ew[i]));
    }
}

// ===========================================================================
// Atomic-free aggregation -> bf16 agg. 32 lanes/node, float4 acc per lane.
// ===========================================================================
__global__ __launch_bounds__(256) void gather_agg_kernel(
    const float* __restrict__ feat, const int2* __restrict__ csr,
    const int* __restrict__ off, unsigned short* __restrict__ aggb, int N)
{
    int g = (int)((blockIdx.x * 256 + threadIdx.x) >> 5);
    if (g >= N) return;
    int q = (threadIdx.x & 31) << 2;
    int beg = off[g], end = off[g + 1];
    float4 acc = make_float4(0.f, 0.f, 0.f, 0.f);
    int i = beg;
    for (; i + 2 <= end; i += 2) {
        int2 e0 = csr[i];
        int2 e1 = csr[i + 1];
        const float4 v0 = *reinterpret_cast<const float4*>(feat + (long)e0.x * D + q);
        const float4 v1 = *reinterpret_cast<const float4*>(feat + (long)e1.x * D + q);
        float w0 = __int_as_float(e0.y), w1 = __int_as_float(e1.y);
        acc.x += v0.x * w0; acc.y += v0.y * w0; acc.z += v0.z * w0; acc.w += v0.w * w0;
        acc.x += v1.x * w1; acc.y += v1.y * w1; acc.z += v1.z * w1; acc.w += v1.w * w1;
    }
    if (i < end) {
        int2 e0 = csr[i];
        const float4 v0 = *reinterpret_cast<const float4*>(feat + (long)e0.x * D + q);
        float w0 = __int_as_float(e0.y);
        acc.x += v0.x * w0; acc.y += v0.y * w0; acc.z += v0.z * w0; acc.w += v0.w * w0;
    }
    ushort4 o;
    o.x = f2bf(acc.x); o.y = f2bf(acc.y); o.z = f2bf(acc.z); o.w = f2bf(acc.w);
    *reinterpret_cast<ushort4*>(aggb + (long)g * D + q) = o;
}

// ===========================================================================
// One-time: W (f32, [k][col]) -> B-fragment-swizzled bf16 buffer.
// Layout: wswz[(((ks*8 + c)*64 + lane)*8 + j)] = bf16(W[ks*32 + (lane>>4)*8 + j][c*16 + (lane&15)])
// ===========================================================================
__global__ __launch_bounds__(256) void prep_w_kernel(
    const float* __restrict__ W, unsigned short* __restrict__ wswz)
{
    int i = blockIdx.x * 256 + threadIdx.x;   // 0..16383
    int j  = i & 7;
    int l  = (i >> 3) & 63;
    int c  = (i >> 9) & 7;
    int ks = i >> 12;
    int k   = ks * 32 + ((l >> 4) * 8) + j;
    int col = c * 16 + (l & 15);
    wswz[i] = f2bf(W[k * D + col]);
}

// ===========================================================================
// MFMA GEMM: h = prelu(agg_bf16 @ W_bf16 + b, a1); store h (f32); col stats.
// Block: 256 thr = 4 waves; wave computes 32 rows x 128 cols via 16x16x32.
// ===========================================================================
__global__ __launch_bounds__(256) void gemm_stats_mfma_kernel(
    const unsigned short* __restrict__ aggb, const unsigned short* __restrict__ wswz,
    const float* __restrict__ bg, const float* __restrict__ a1p,
    float* __restrict__ hout, float* __restrict__ stats, int N)
{
    __shared__ unsigned short Bl[16384];   // 32 KB: fragment-ready W
    __shared__ float sblk[2][D];

    int t = threadIdx.x;
    for (int i = t; i < 2048; i += 256)
        reinterpret_cast<float4*>(Bl)[i] = reinterpret_cast<const float4*>(wswz)[i];
    if (t < D) { sblk[0][t] = 0.f; sblk[1][t] = 0.f; }
    __syncthreads();

    const int lane = t & 63;
    const int wv   = t >> 6;
    const long rbase = (long)blockIdx.x * 128 + wv * 32;
    const int lr = lane & 15;     // A-row / C-col index
    const int lk = lane >> 4;     // k-group

    f32x4 acc[2][8];
    #pragma unroll
    for (int rt = 0; rt < 2; ++rt)
        #pragma unroll
        for (int c = 0; c < 8; ++c)
            acc[rt][c] = (f32x4){0.f, 0.f, 0.f, 0.f};

    long r0 = rbase + lr;
    long r1 = rbase + 16 + lr;
    long r0c = (r0 < N) ? r0 : 0;
    long r1c = (r1 < N) ? r1 : 0;

    #pragma unroll
    for (int ks = 0; ks < 4; ++ks) {
        bf16x8 a0 = *reinterpret_cast<const bf16x8*>(aggb + r0c * D + ks * 32 + lk * 8);
        bf16x8 a1f = *reinterpret_cast<const bf16x8*>(aggb + r1c * D + ks * 32 + lk * 8);
        #pragma unroll
        for (int c = 0; c < 8; ++c) {
            bf16x8 bfr = *reinterpret_cast<const bf16x8*>(&Bl[((ks * 8 + c) * 64 + lane) * 8]);
            acc[0][c] = __builtin_amdgcn_mfma_f32_16x16x32_bf16(a0, bfr, acc[0][c], 0, 0, 0);
            acc[1][c] = __builtin_amdgcn_mfma_f32_16x16x32_bf16(a1f, bfr, acc[1][c], 0, 0, 0);
        }
    }

    // epilogue: bias + PReLU(a1), store f32 h, per-col stats
    const float a1v = a1p[0];
    float bias[8];
    #pragma unroll
    for (int c = 0; c < 8; ++c) bias[c] = bg[c * 16 + lr];

    float csum[8] = {0,0,0,0,0,0,0,0};
    float csq[8]  = {0,0,0,0,0,0,0,0};
    #pragma unroll
    for (int rt = 0; rt < 2; ++rt) {
        #pragma unroll
        for (int reg = 0; reg < 4; ++reg) {
            long row = rbase + rt * 16 + lk * 4 + reg;
            if (row >= N) continue;
            #pragma unroll
            for (int c = 0; c < 8; ++c) {
                float v = acc[rt][c][reg] + bias[c];
                v = v >= 0.f ? v : v * a1v;
                hout[row * D + c * 16 + lr] = v;
                csum[c] += v;
                csq[c]  += v * v;
            }
        }
    }
    #pragma unroll
    for (int c = 0; c < 8; ++c) {
        atomicAdd(&sblk[0][c * 16 + lr], csum[c]);
        atomicAdd(&sblk[1][c * 16 + lr], csq[c]);
    }
    __syncthreads();
    if (t < D) {
        atomicAdd(&stats[t],     sblk[0][t]);
        atomicAdd(&stats[D + t], sblk[1][t]);
    }
}

// ===========================================================================
// Fallback path kernels (ws too small for CSR): f32 atomic scatter + f32 GEMM.
// ===========================================================================
__global__ __launch_bounds__(256) void scatter_kernel(
    const float* __restrict__ feat, const int* __restrict__ src,
    const int* __restrict__ dst, const float* __restrict__ ew,
    float* __restrict__ agg, int E)
{
    long tid = (long)blockIdx.x * blockDim.x + threadIdx.x;
    int e = (int)(tid >> 5);
    if (e >= E) return;
    int q = ((int)tid & 31) << 2;
    int s = src[e];
    int d = dst[e];
    float w = ew[e];
    float4 v = *reinterpret_cast<const float4*>(feat + (long)s * D + q);
    float* o = agg + (long)d * D + q;
    atomicAdd(o + 0, v.x * w);
    atomicAdd(o + 1, v.y * w);
    atomicAdd(o + 2, v.z * w);
    atomicAdd(o + 3, v.w * w);
}

__global__ __launch_bounds__(256) void gemm_stats_kernel(
    const float* __restrict__ agg, const float* __restrict__ Wg,
    const float* __restrict__ bg, const float* __restrict__ a1,
    float* __restrict__ hout, float* __restrict__ stats, int N)
{
    __shared__ float Wl[D * D];
    __shared__ float sblk[2][D];

    int t = threadIdx.x;
    for (int i = t; i < D * D / 4; i += 256) {
        reinterpret_cast<float4*>(Wl)[i] =
            reinterpret_cast<const float4*>(Wg)[i];
    }
    if (t < D) { sblk[0][t] = 0.f; sblk[1][t] = 0.f; }
    __syncthreads();

    const int c0 = (t & 31) << 2;
    const int rbase = blockIdx.x * 32 + (t >> 5) * 4;
    const float a1v = a1[0];

    bool valid[4];
    #pragma unroll
    for (int i = 0; i < 4; ++i) valid[i] = (rbase + i) < N;

    float acc[4][4];
    float4 bv = *reinterpret_cast<const float4*>(bg + c0);
    #pragma unroll
    for (int i = 0; i < 4; ++i) {
        acc[i][0] = bv.x; acc[i][1] = bv.y; acc[i][2] = bv.z; acc[i][3] = bv.w;
    }

    for (int k0 = 0; k0 < D; k0 += 4) {
        float4 a[4];
        #pragma unroll
        for (int i = 0; i < 4; ++i) {
            a[i] = valid[i]
                ? *reinterpret_cast<const float4*>(agg + (long)(rbase + i) * D + k0)
                : make_float4(0.f, 0.f, 0.f, 0.f);
        }
        #pragma unroll
        for (int kk = 0; kk < 4; ++kk) {
            float4 wv = *reinterpret_cast<const float4*>(&Wl[(k0 + kk) * D + c0]);
            #pragma unroll
            for (int i = 0; i < 4; ++i) {
                float av = kk == 0 ? a[i].x : kk == 1 ? a[i].y : kk == 2 ? a[i].z : a[i].w;
                acc[i][0] += av * wv.x;
                acc[i][1] += av * wv.y;
                acc[i][2] += av * wv.z;
                acc[i][3] += av * wv.w;
            }
        }
    }

    float csum[4] = {0.f, 0.f, 0.f, 0.f};
    float csq[4]  = {0.f, 0.f, 0.f, 0.f};
    #pragma unroll
    for (int i = 0; i < 4; ++i) {
        if (!valid[i]) continue;
        float4 o;
        #pragma unroll
        for (int j = 0; j < 4; ++j) {
            float v = acc[i][j];
            v = v >= 0.f ? v : v * a1v;
            (&o.x)[j] = v;
            csum[j] += v;
            csq[j]  += v * v;
        }
        *reinterpret_cast<float4*>(hout + (long)(rbase + i) * D + c0) = o;
    }
    #pragma unroll
    for (int j = 0; j < 4; ++j) {
        atomicAdd(&sblk[0][c0 + j], csum[j]);
        atomicAdd(&sblk[1][c0 + j], csq[j]);
    }
    __syncthreads();
    if (t < D) {
        atomicAdd(&stats[t],     sblk[0][t]);
        atomicAdd(&stats[D + t], sblk[1][t]);
    }
}

// ===========================================================================
__global__ void finalize_kernel(const float* __restrict__ stats,
                                const float* __restrict__ gamma,
                                const float* __restrict__ beta,
                                float* __restrict__ ss, int N)
{
    int c = threadIdx.x;
    float invN = 1.0f / (float)N;
    float mean = stats[c] * invN;
    float var  = stats[D + c] * invN - mean * mean;
    float sc = gamma[c] * rsqrtf(var + BN_EPS);
    ss[c]     = sc;
    ss[D + c] = beta[c] - mean * sc;
}

__global__ __launch_bounds__(256) void bn_prelu_kernel(
    float* __restrict__ h, const float* __restrict__ ss,
    const float* __restrict__ a2, long n4)
{
    const float a2v = a2[0];
    long i = (long)blockIdx.x * blockDim.x + threadIdx.x;
    long stride = (long)gridDim.x * blockDim.x;
    for (; i < n4; i += stride) {
        float4 x = reinterpret_cast<float4*>(h)[i];
        int c0 = ((int)(i & 31)) << 2;
        float4 sc = *reinterpret_cast<const float4*>(ss + c0);
        float4 sh = *reinterpret_cast<const float4*>(ss + D + c0);
        float v;
        v = x.x * sc.x + sh.x; x.x = v >= 0.f ? v : v * a2v;
        v = x.y * sc.y + sh.y; x.y = v >= 0.f ? v : v * a2v;
        v = x.z * sc.z + sh.z; x.z = v >= 0.f ? v : v * a2v;
        v = x.w * sc.w + sh.w; x.w = v >= 0.f ? v : v * a2v;
        reinterpret_cast<float4*>(h)[i] = x;
    }
}

// ===========================================================================
extern "C" void kernel_launch(void* const* d_in, const int* in_sizes, int n_in,
                              void* d_out, int out_size, void* d_ws, size_t ws_size,
                              hipStream_t stream)
{
    const float* feat  = (const float*)d_in[0];
    const int*   src   = (const int*)d_in[1];
    const int*   dst   = (const int*)d_in[2];
    const float* ew    = (const float*)d_in[3];
    const float* W     = (const float*)d_in[4];
    const float* b     = (const float*)d_in[5];
    const float* a1    = (const float*)d_in[6];
    const float* gamma = (const float*)d_in[7];
    const float* beta  = (const float*)d_in[8];
    const float* a2    = (const float*)d_in[9];

    const int N = in_sizes[0] / D;
    const int E = in_sizes[1];

    // ws layout (16B-aligned chunks)
    char* p = (char*)d_ws;
    unsigned short* aggb = (unsigned short*)p; p += (size_t)N * D * sizeof(unsigned short);
    int2*  csr = (int2*)p;                p += (size_t)E * sizeof(int2);
    int*   deg = (int*)p;                 p += (size_t)((N + 3) & ~3) * sizeof(int);   // cursor
    int*   off = (int*)p;                 p += (size_t)((N + 5) & ~3) * sizeof(int);
    int*   bsum = (int*)p;                p += 1024 * sizeof(int);
    unsigned short* wswz = (unsigned short*)p; p += 16384 * sizeof(unsigned short);
    float* stats = (float*)p;             p += 2 * D * sizeof(float);
    float* ss    = (float*)p;             p += 2 * D * sizeof(float);
    size_t need = (size_t)(p - (char*)d_ws);
    float* out = (float*)d_out;

    int nb = (N + 1023) / 1024;

    if (ws_size >= need && nb <= 1024) {
        // ---- CSR + MFMA path ----
        hipMemsetAsync(deg, 0, (size_t)N * sizeof(int), stream);
        hipMemsetAsync(stats, 0, 2 * D * sizeof(float), stream);
        hist_kernel<<<2048, 256, 0, stream>>>(dst, deg, E);
        scan_block_kernel<<<nb, 256, 0, stream>>>(deg, off, bsum, N);
        scan_bsum_kernel<<<1, 1024, 0, stream>>>(bsum, nb);
        add_off_kernel<<<nb, 256, 0, stream>>>(off, bsum, deg, N, E);
        reorder_kernel<<<2048, 256, 0, stream>>>(src, dst, ew, deg, csr, E);
        int ablocks = (int)(((long)N * 32 + 255) / 256);
        gather_agg_kernel<<<ablocks, 256, 0, stream>>>(feat, csr, off, aggb, N);
        prep_w_kernel<<<64, 256, 0, stream>>>(W, wswz);
        int gblocks = (N + 127) / 128;
        gemm_stats_mfma_kernel<<<gblocks, 256, 0, stream>>>(aggb, wswz, b, a1, out, stats, N);
    } else {
        // ---- fallback: f32 atomic scatter + f32 GEMM ----
        float* agg = (float*)d_ws;
        stats = agg + (size_t)N * D;
        ss    = stats + 2 * D;
        hipMemsetAsync(agg, 0, ((size_t)N * D + 2 * D) * sizeof(float), stream);
        long nthreads = (long)E * 32;
        int sblocks = (int)((nthreads + 255) / 256);
        scatter_kernel<<<sblocks, 256, 0, stream>>>(feat, src, dst, ew, agg, E);
        int gblocks = (N + 31) / 32;
        gemm_stats_kernel<<<gblocks, 256, 0, stream>>>(agg, W, b, a1, out, stats, N);
    }

    finalize_kernel<<<1, D, 0, stream>>>(stats, gamma, beta, ss, N);
    long n4 = (long)N * D / 4;
    bn_prelu_kernel<<<2048, 256, 0, stream>>>(out, ss, a2, n4);
}

// Round 5
// 312.018 us; speedup vs baseline: 9.3042x; 1.2277x over previous
//
#include <hip/hip_runtime.h>

#define D 128
#define BN_EPS 1e-5f
#define CHUNK 8192
#define MAXSEG 6144
#define MAXNB 4096

typedef __attribute__((ext_vector_type(8))) short bf16x8;
typedef __attribute__((ext_vector_type(4))) float f32x4;

__device__ __forceinline__ unsigned short f2bf(float f) {
    unsigned int u = __float_as_uint(f);
    u += 0x7FFFu + ((u >> 16) & 1u);
    return (unsigned short)(u >> 16);
}

// ===========================================================================
// CSR-by-dst build: histogram -> hierarchical scan -> bucket partition
// ===========================================================================

__global__ __launch_bounds__(256) void hist_kernel(
    const int* __restrict__ dst, int* __restrict__ deg, int E)
{
    int i = blockIdx.x * 256 + threadIdx.x;
    int stride = gridDim.x * 256;
    for (; i < E; i += stride) atomicAdd(&deg[dst[i]], 1);
}

__global__ __launch_bounds__(256) void scan_block_kernel(
    const int* __restrict__ deg, int* __restrict__ off,
    int* __restrict__ bsum, int N)
{
    __shared__ int lsum[256];
    int t = threadIdx.x;
    int base = blockIdx.x * 1024 + t * 4;
    int4 v = make_int4(0, 0, 0, 0);
    if (base + 3 < N) {
        v = *reinterpret_cast<const int4*>(deg + base);
    } else {
        if (base + 0 < N) v.x = deg[base + 0];
        if (base + 1 < N) v.y = deg[base + 1];
        if (base + 2 < N) v.z = deg[base + 2];
        if (base + 3 < N) v.w = deg[base + 3];
    }
    int s = v.x + v.y + v.z + v.w;
    lsum[t] = s;
    __syncthreads();
    for (int d = 1; d < 256; d <<= 1) {
        int val = (t >= d) ? lsum[t - d] : 0;
        __syncthreads();
        lsum[t] += val;
        __syncthreads();
    }
    int run = lsum[t] - s;
    if (t == 255) bsum[blockIdx.x] = lsum[t];
    if (base + 0 < N) { off[base + 0] = run; run += v.x; }
    if (base + 1 < N) { off[base + 1] = run; run += v.y; }
    if (base + 2 < N) { off[base + 2] = run; run += v.z; }
    if (base + 3 < N) { off[base + 3] = run; run += v.w; }
}

__global__ __launch_bounds__(1024) void scan_bsum_kernel(int* bsum, int nb)
{
    __shared__ int l[1024];
    int t = threadIdx.x;
    int v = (t < nb) ? bsum[t] : 0;
    l[t] = v;
    __syncthreads();
    for (int d = 1; d < 1024; d <<= 1) {
        int val = (t >= d) ? l[t - d] : 0;
        __syncthreads();
        l[t] += val;
        __syncthreads();
    }
    if (t < nb) bsum[t] = l[t] - v;
}

__global__ __launch_bounds__(256) void add_off_kernel(
    int* __restrict__ off, const int* __restrict__ bsum,
    int* __restrict__ cursor, int N, int E)
{
    int bo = bsum[blockIdx.x];
    int base = blockIdx.x * 1024 + threadIdx.x * 4;
    #pragma unroll
    for (int j = 0; j < 4; ++j) {
        int i = base + j;
        if (i < N) { int o = off[i] + bo; off[i] = o; cursor[i] = o; }
    }
    if (blockIdx.x == 0 && threadIdx.x == 0) off[N] = E;
}

// bucket cursors: bcur[k] = off[min(k*256, N)]
__global__ __launch_bounds__(256) void init_bcur_kernel(
    const int* __restrict__ off, int* __restrict__ bcur, int N, int NB)
{
    int k = blockIdx.x * 256 + threadIdx.x;
    if (k < NB) {
        int node = k << 8;
        bcur[k] = off[node < N ? node : N];
    }
}

// ---------------------------------------------------------------------------
// Pass A: partition edges into 256-node buckets. Entry = {src | dstlow<<20, w}.
// Per chunk: LDS count -> 1 global reserve per bucket -> run-clustered writes.
// ---------------------------------------------------------------------------
__global__ __launch_bounds__(256) void pass_a_kernel(
    const int* __restrict__ src, const int* __restrict__ dst,
    const float* __restrict__ ew, int* __restrict__ bcur,
    int2* __restrict__ csr, int E, int NB)
{
    __shared__ int lcnt[MAXNB];
    __shared__ int lcur[MAXNB];
    int nchunks = (E + CHUNK - 1) / CHUNK;
    int t = threadIdx.x;
    for (int c = blockIdx.x; c < nchunks; c += gridDim.x) {
        int base = c * CHUNK;
        int lim = min(CHUNK, E - base);
        for (int k = t; k < NB; k += 256) lcnt[k] = 0;
        __syncthreads();
        for (int j = t; j < lim; j += 256)
            atomicAdd(&lcnt[dst[base + j] >> 8], 1);
        __syncthreads();
        for (int k = t; k < NB; k += 256) {
            int cnt = lcnt[k];
            lcur[k] = cnt > 0 ? atomicAdd(&bcur[k], cnt) : 0;
        }
        __syncthreads();
        for (int j = t; j < lim; j += 256) {
            int e = base + j;
            int dv = dst[e];
            int p = atomicAdd(&lcur[dv >> 8], 1);
            csr[p] = make_int2((src[e] & 0xFFFFF) | ((dv & 255) << 20),
                               __float_as_int(ew[e]));
        }
        __syncthreads();
    }
}

// ---------------------------------------------------------------------------
// Pass B: per bucket, counting-scatter segment into per-node order via LDS;
// strip packed dst bits. In-place (reads done before writes). Oversized
// buckets flagged for pass_b_big.
// ---------------------------------------------------------------------------
__global__ __launch_bounds__(256) void pass_b_kernel(
    int2* __restrict__ csr, const int* __restrict__ off,
    int* __restrict__ ovf, int N)
{
    __shared__ int2 sout[MAXSEG];
    __shared__ int lcur[256];
    int k = blockIdx.x;
    int nlo = k << 8;
    int nhi = min(nlo + 256, N);
    int segbeg = off[nlo], segend = off[nhi];
    int len = segend - segbeg;
    int t = threadIdx.x;
    if (t == 0) ovf[k] = (len > MAXSEG) ? 1 : 0;
    if (len > MAXSEG) return;
    if (nlo + t < nhi) lcur[t] = off[nlo + t] - segbeg;
    __syncthreads();
    for (int j = t; j < len; j += 256) {
        int2 e = csr[segbeg + j];
        int slot = (e.x >> 20) & 255;
        int p = atomicAdd(&lcur[slot], 1);
        sout[p] = make_int2(e.x & 0xFFFFF, e.y);
    }
    __syncthreads();
    for (int j = t; j < len; j += 256)
        csr[segbeg + j] = sout[j];
}

// Rare fallback for oversized buckets: bounce via tmp (aggb region), global
// per-node cursors (initialized to off[] by add_off).
__global__ __launch_bounds__(256) void pass_b_big_kernel(
    int2* __restrict__ csr, const int* __restrict__ off,
    const int* __restrict__ ovf, int* __restrict__ gcur,
    int2* __restrict__ tmp, int N)
{
    int k = blockIdx.x;
    if (!ovf[k]) return;
    int nlo = k << 8;
    int nhi = min(nlo + 256, N);
    int segbeg = off[nlo], segend = off[nhi];
    int len = segend - segbeg;
    int t = threadIdx.x;
    for (int j = t; j < len; j += 256) tmp[segbeg + j] = csr[segbeg + j];
    __syncthreads();
    for (int j = t; j < len; j += 256) {
        int2 e = tmp[segbeg + j];
        int node = nlo + ((e.x >> 20) & 255);
        int p = atomicAdd(&gcur[node], 1);
        csr[p] = make_int2(e.x & 0xFFFFF, e.y);
    }
}

// ===========================================================================
// Atomic-free aggregation -> bf16 agg. 32 lanes/node, float4 acc per lane.
// ===========================================================================
__global__ __launch_bounds__(256) void gather_agg_kernel(
    const float* __restrict__ feat, const int2* __restrict__ csr,
    const int* __restrict__ off, unsigned short* __restrict__ aggb, int N)
{
    int g = (int)((blockIdx.x * 256 + threadIdx.x) >> 5);
    if (g >= N) return;
    int q = (threadIdx.x & 31) << 2;
    int beg = off[g], end = off[g + 1];
    float4 acc = make_float4(0.f, 0.f, 0.f, 0.f);
    int i = beg;
    for (; i + 2 <= end; i += 2) {
        int2 e0 = csr[i];
        int2 e1 = csr[i + 1];
        const float4 v0 = *reinterpret_cast<const float4*>(feat + (long)e0.x * D + q);
        const float4 v1 = *reinterpret_cast<const float4*>(feat + (long)e1.x * D + q);
        float w0 = __int_as_float(e0.y), w1 = __int_as_float(e1.y);
        acc.x += v0.x * w0; acc.y += v0.y * w0; acc.z += v0.z * w0; acc.w += v0.w * w0;
        acc.x += v1.x * w1; acc.y += v1.y * w1; acc.z += v1.z * w1; acc.w += v1.w * w1;
    }
    if (i < end) {
        int2 e0 = csr[i];
        const float4 v0 = *reinterpret_cast<const float4*>(feat + (long)e0.x * D + q);
        float w0 = __int_as_float(e0.y);
        acc.x += v0.x * w0; acc.y += v0.y * w0; acc.z += v0.z * w0; acc.w += v0.w * w0;
    }
    ushort4 o;
    o.x = f2bf(acc.x); o.y = f2bf(acc.y); o.z = f2bf(acc.z); o.w = f2bf(acc.w);
    *reinterpret_cast<ushort4*>(aggb + (long)g * D + q) = o;
}

// ===========================================================================
// One-time: W (f32, [k][col]) -> B-fragment-swizzled bf16 buffer.
// ===========================================================================
__global__ __launch_bounds__(256) void prep_w_kernel(
    const float* __restrict__ W, unsigned short* __restrict__ wswz)
{
    int i = blockIdx.x * 256 + threadIdx.x;   // 0..16383
    int j  = i & 7;
    int l  = (i >> 3) & 63;
    int c  = (i >> 9) & 7;
    int ks = i >> 12;
    int k   = ks * 32 + ((l >> 4) * 8) + j;
    int col = c * 16 + (l & 15);
    wswz[i] = f2bf(W[k * D + col]);
}

// ===========================================================================
// MFMA GEMM: h = prelu(agg_bf16 @ W_bf16 + b, a1); store h (f32); col stats.
// ===========================================================================
__global__ __launch_bounds__(256) void gemm_stats_mfma_kernel(
    const unsigned short* __restrict__ aggb, const unsigned short* __restrict__ wswz,
    const float* __restrict__ bg, const float* __restrict__ a1p,
    float* __restrict__ hout, float* __restrict__ stats, int N)
{
    __shared__ unsigned short Bl[16384];   // 32 KB: fragment-ready W
    __shared__ float sblk[2][D];

    int t = threadIdx.x;
    for (int i = t; i < 2048; i += 256)
        reinterpret_cast<float4*>(Bl)[i] = reinterpret_cast<const float4*>(wswz)[i];
    if (t < D) { sblk[0][t] = 0.f; sblk[1][t] = 0.f; }
    __syncthreads();

    const int lane = t & 63;
    const int wv   = t >> 6;
    const long rbase = (long)blockIdx.x * 128 + wv * 32;
    const int lr = lane & 15;
    const int lk = lane >> 4;

    f32x4 acc[2][8];
    #pragma unroll
    for (int rt = 0; rt < 2; ++rt)
        #pragma unroll
        for (int c = 0; c < 8; ++c)
            acc[rt][c] = (f32x4){0.f, 0.f, 0.f, 0.f};

    long r0 = rbase + lr;
    long r1 = rbase + 16 + lr;
    long r0c = (r0 < N) ? r0 : 0;
    long r1c = (r1 < N) ? r1 : 0;

    #pragma unroll
    for (int ks = 0; ks < 4; ++ks) {
        bf16x8 a0 = *reinterpret_cast<const bf16x8*>(aggb + r0c * D + ks * 32 + lk * 8);
        bf16x8 a1f = *reinterpret_cast<const bf16x8*>(aggb + r1c * D + ks * 32 + lk * 8);
        #pragma unroll
        for (int c = 0; c < 8; ++c) {
            bf16x8 bfr = *reinterpret_cast<const bf16x8*>(&Bl[((ks * 8 + c) * 64 + lane) * 8]);
            acc[0][c] = __builtin_amdgcn_mfma_f32_16x16x32_bf16(a0, bfr, acc[0][c], 0, 0, 0);
            acc[1][c] = __builtin_amdgcn_mfma_f32_16x16x32_bf16(a1f, bfr, acc[1][c], 0, 0, 0);
        }
    }

    const float a1v = a1p[0];
    float bias[8];
    #pragma unroll
    for (int c = 0; c < 8; ++c) bias[c] = bg[c * 16 + lr];

    float csum[8] = {0,0,0,0,0,0,0,0};
    float csq[8]  = {0,0,0,0,0,0,0,0};
    #pragma unroll
    for (int rt = 0; rt < 2; ++rt) {
        #pragma unroll
        for (int reg = 0; reg < 4; ++reg) {
            long row = rbase + rt * 16 + lk * 4 + reg;
            if (row >= N) continue;
            #pragma unroll
            for (int c = 0; c < 8; ++c) {
                float v = acc[rt][c][reg] + bias[c];
                v = v >= 0.f ? v : v * a1v;
                hout[row * D + c * 16 + lr] = v;
                csum[c] += v;
                csq[c]  += v * v;
            }
        }
    }
    #pragma unroll
    for (int c = 0; c < 8; ++c) {
        atomicAdd(&sblk[0][c * 16 + lr], csum[c]);
        atomicAdd(&sblk[1][c * 16 + lr], csq[c]);
    }
    __syncthreads();
    if (t < D) {
        atomicAdd(&stats[t],     sblk[0][t]);
        atomicAdd(&stats[D + t], sblk[1][t]);
    }
}

// ===========================================================================
// Fallback path kernels (ws too small): f32 atomic scatter + f32 GEMM.
// ===========================================================================
__global__ __launch_bounds__(256) void scatter_kernel(
    const float* __restrict__ feat, const int* __restrict__ src,
    const int* __restrict__ dst, const float* __restrict__ ew,
    float* __restrict__ agg, int E)
{
    long tid = (long)blockIdx.x * blockDim.x + threadIdx.x;
    int e = (int)(tid >> 5);
    if (e >= E) return;
    int q = ((int)tid & 31) << 2;
    int s = src[e];
    int d = dst[e];
    float w = ew[e];
    float4 v = *reinterpret_cast<const float4*>(feat + (long)s * D + q);
    float* o = agg + (long)d * D + q;
    atomicAdd(o + 0, v.x * w);
    atomicAdd(o + 1, v.y * w);
    atomicAdd(o + 2, v.z * w);
    atomicAdd(o + 3, v.w * w);
}

__global__ __launch_bounds__(256) void gemm_stats_kernel(
    const float* __restrict__ agg, const float* __restrict__ Wg,
    const float* __restrict__ bg, const float* __restrict__ a1,
    float* __restrict__ hout, float* __restrict__ stats, int N)
{
    __shared__ float Wl[D * D];
    __shared__ float sblk[2][D];

    int t = threadIdx.x;
    for (int i = t; i < D * D / 4; i += 256) {
        reinterpret_cast<float4*>(Wl)[i] =
            reinterpret_cast<const float4*>(Wg)[i];
    }
    if (t < D) { sblk[0][t] = 0.f; sblk[1][t] = 0.f; }
    __syncthreads();

    const int c0 = (t & 31) << 2;
    const int rbase = blockIdx.x * 32 + (t >> 5) * 4;
    const float a1v = a1[0];

    bool valid[4];
    #pragma unroll
    for (int i = 0; i < 4; ++i) valid[i] = (rbase + i) < N;

    float acc[4][4];
    float4 bv = *reinterpret_cast<const float4*>(bg + c0);
    #pragma unroll
    for (int i = 0; i < 4; ++i) {
        acc[i][0] = bv.x; acc[i][1] = bv.y; acc[i][2] = bv.z; acc[i][3] = bv.w;
    }

    for (int k0 = 0; k0 < D; k0 += 4) {
        float4 a[4];
        #pragma unroll
        for (int i = 0; i < 4; ++i) {
            a[i] = valid[i]
                ? *reinterpret_cast<const float4*>(agg + (long)(rbase + i) * D + k0)
                : make_float4(0.f, 0.f, 0.f, 0.f);
        }
        #pragma unroll
        for (int kk = 0; kk < 4; ++kk) {
            float4 wv = *reinterpret_cast<const float4*>(&Wl[(k0 + kk) * D + c0]);
            #pragma unroll
            for (int i = 0; i < 4; ++i) {
                float av = kk == 0 ? a[i].x : kk == 1 ? a[i].y : kk == 2 ? a[i].z : a[i].w;
                acc[i][0] += av * wv.x;
                acc[i][1] += av * wv.y;
                acc[i][2] += av * wv.z;
                acc[i][3] += av * wv.w;
            }
        }
    }

    float csum[4] = {0.f, 0.f, 0.f, 0.f};
    float csq[4]  = {0.f, 0.f, 0.f, 0.f};
    #pragma unroll
    for (int i = 0; i < 4; ++i) {
        if (!valid[i]) continue;
        float4 o;
        #pragma unroll
        for (int j = 0; j < 4; ++j) {
            float v = acc[i][j];
            v = v >= 0.f ? v : v * a1v;
            (&o.x)[j] = v;
            csum[j] += v;
            csq[j]  += v * v;
        }
        *reinterpret_cast<float4*>(hout + (long)(rbase + i) * D + c0) = o;
    }
    #pragma unroll
    for (int j = 0; j < 4; ++j) {
        atomicAdd(&sblk[0][c0 + j], csum[j]);
        atomicAdd(&sblk[1][c0 + j], csq[j]);
    }
    __syncthreads();
    if (t < D) {
        atomicAdd(&stats[t],     sblk[0][t]);
        atomicAdd(&stats[D + t], sblk[1][t]);
    }
}

// ===========================================================================
__global__ void finalize_kernel(const float* __restrict__ stats,
                                const float* __restrict__ gamma,
                                const float* __restrict__ beta,
                                float* __restrict__ ss, int N)
{
    int c = threadIdx.x;
    float invN = 1.0f / (float)N;
    float mean = stats[c] * invN;
    float var  = stats[D + c] * invN - mean * mean;
    float sc = gamma[c] * rsqrtf(var + BN_EPS);
    ss[c]     = sc;
    ss[D + c] = beta[c] - mean * sc;
}

__global__ __launch_bounds__(256) void bn_prelu_kernel(
    float* __restrict__ h, const float* __restrict__ ss,
    const float* __restrict__ a2, long n4)
{
    const float a2v = a2[0];
    long i = (long)blockIdx.x * blockDim.x + threadIdx.x;
    long stride = (long)gridDim.x * blockDim.x;
    for (; i < n4; i += stride) {
        float4 x = reinterpret_cast<float4*>(h)[i];
        int c0 = ((int)(i & 31)) << 2;
        float4 sc = *reinterpret_cast<const float4*>(ss + c0);
        float4 sh = *reinterpret_cast<const float4*>(ss + D + c0);
        float v;
        v = x.x * sc.x + sh.x; x.x = v >= 0.f ? v : v * a2v;
        v = x.y * sc.y + sh.y; x.y = v >= 0.f ? v : v * a2v;
        v = x.z * sc.z + sh.z; x.z = v >= 0.f ? v : v * a2v;
        v = x.w * sc.w + sh.w; x.w = v >= 0.f ? v : v * a2v;
        reinterpret_cast<float4*>(h)[i] = x;
    }
}

// ===========================================================================
extern "C" void kernel_launch(void* const* d_in, const int* in_sizes, int n_in,
                              void* d_out, int out_size, void* d_ws, size_t ws_size,
                              hipStream_t stream)
{
    const float* feat  = (const float*)d_in[0];
    const int*   src   = (const int*)d_in[1];
    const int*   dst   = (const int*)d_in[2];
    const float* ew    = (const float*)d_in[3];
    const float* W     = (const float*)d_in[4];
    const float* b     = (const float*)d_in[5];
    const float* a1    = (const float*)d_in[6];
    const float* gamma = (const float*)d_in[7];
    const float* beta  = (const float*)d_in[8];
    const float* a2    = (const float*)d_in[9];

    const int N = in_sizes[0] / D;
    const int E = in_sizes[1];

    // ws layout (16B-aligned chunks)
    char* p = (char*)d_ws;
    unsigned short* aggb = (unsigned short*)p; p += (size_t)N * D * sizeof(unsigned short);
    int2*  csr = (int2*)p;                p += (size_t)E * sizeof(int2);
    int*   deg = (int*)p;                 p += (size_t)((N + 3) & ~3) * sizeof(int);   // gcur
    int*   off = (int*)p;                 p += (size_t)((N + 5) & ~3) * sizeof(int);
    int*   bsum = (int*)p;                p += 1024 * sizeof(int);
    int*   bcur = (int*)p;                p += MAXNB * sizeof(int);
    int*   ovf  = (int*)p;                p += MAXNB * sizeof(int);
    unsigned short* wswz = (unsigned short*)p; p += 16384 * sizeof(unsigned short);
    float* stats = (float*)p;             p += 2 * D * sizeof(float);
    float* ss    = (float*)p;             p += 2 * D * sizeof(float);
    size_t need = (size_t)(p - (char*)d_ws);
    float* out = (float*)d_out;

    int nb = (N + 1023) / 1024;           // scan level-1 blocks
    int NB = (N + 255) / 256;             // partition buckets

    if (ws_size >= need && nb <= 1024) {
        // ---- CSR + MFMA path ----
        hipMemsetAsync(deg, 0, (size_t)N * sizeof(int), stream);
        hipMemsetAsync(stats, 0, 2 * D * sizeof(float), stream);
        hist_kernel<<<2048, 256, 0, stream>>>(dst, deg, E);
        scan_block_kernel<<<nb, 256, 0, stream>>>(deg, off, bsum, N);
        scan_bsum_kernel<<<1, 1024, 0, stream>>>(bsum, nb);
        add_off_kernel<<<nb, 256, 0, stream>>>(off, bsum, deg, N, E);
        init_bcur_kernel<<<(NB + 255) / 256, 256, 0, stream>>>(off, bcur, N, NB);
        int nchunks = (E + CHUNK - 1) / CHUNK;
        pass_a_kernel<<<min(nchunks, 1024), 256, 0, stream>>>(src, dst, ew, bcur, csr, E, NB);
        pass_b_kernel<<<NB, 256, 0, stream>>>(csr, off, ovf, N);
        pass_b_big_kernel<<<NB, 256, 0, stream>>>(csr, off, ovf, deg, (int2*)aggb, N);
        int ablocks = (int)(((long)N * 32 + 255) / 256);
        gather_agg_kernel<<<ablocks, 256, 0, stream>>>(feat, csr, off, aggb, N);
        prep_w_kernel<<<64, 256, 0, stream>>>(W, wswz);
        int gblocks = (N + 127) / 128;
        gemm_stats_mfma_kernel<<<gblocks, 256, 0, stream>>>(aggb, wswz, b, a1, out, stats, N);
    } else {
        // ---- fallback: f32 atomic scatter + f32 GEMM ----
        float* agg = (float*)d_ws;
        stats = agg + (size_t)N * D;
        ss    = stats + 2 * D;
        hipMemsetAsync(agg, 0, ((size_t)N * D + 2 * D) * sizeof(float), stream);
        long nthreads = (long)E * 32;
        int sblocks = (int)((nthreads + 255) / 256);
        scatter_kernel<<<sblocks, 256, 0, stream>>>(feat, src, dst, ew, agg, E);
        int gblocks = (N + 31) / 32;
        gemm_stats_kernel<<<gblocks, 256, 0, stream>>>(agg, W, b, a1, out, stats, N);
    }

    finalize_kernel<<<1, D, 0, stream>>>(stats, gamma, beta, ss, N);
    long n4 = (long)N * D / 4;
    bn_prelu_kernel<<<2048, 256, 0, stream>>>(out, ss, a2, n4);
}

// Round 6
// 278.054 us; speedup vs baseline: 10.4407x; 1.1221x over previous
//
#include <hip/hip_runtime.h>

#define D 128
#define BN_EPS 1e-5f
#define CHUNK 8192
#define MAXSEG 6144
#define MAXNB 4096

typedef __attribute__((ext_vector_type(8))) short bf16x8;
typedef __attribute__((ext_vector_type(8))) unsigned short u16x8;
typedef __attribute__((ext_vector_type(4))) float f32x4;

__device__ __forceinline__ unsigned short f2bf(float f) {
    unsigned int u = __float_as_uint(f);
    u += 0x7FFFu + ((u >> 16) & 1u);
    return (unsigned short)(u >> 16);
}
__device__ __forceinline__ float bf2f(unsigned short u) {
    return __uint_as_float(((unsigned int)u) << 16);
}

// ===========================================================================
// CSR-by-dst build: histogram -> hierarchical scan -> bucket partition
// ===========================================================================

__global__ __launch_bounds__(256) void hist_kernel(
    const int* __restrict__ dst, int* __restrict__ deg, int E)
{
    int i = blockIdx.x * 256 + threadIdx.x;
    int stride = gridDim.x * 256;
    for (; i < E; i += stride) atomicAdd(&deg[dst[i]], 1);
}

__global__ __launch_bounds__(256) void scan_block_kernel(
    const int* __restrict__ deg, int* __restrict__ off,
    int* __restrict__ bsum, int N)
{
    __shared__ int lsum[256];
    int t = threadIdx.x;
    int base = blockIdx.x * 1024 + t * 4;
    int4 v = make_int4(0, 0, 0, 0);
    if (base + 3 < N) {
        v = *reinterpret_cast<const int4*>(deg + base);
    } else {
        if (base + 0 < N) v.x = deg[base + 0];
        if (base + 1 < N) v.y = deg[base + 1];
        if (base + 2 < N) v.z = deg[base + 2];
        if (base + 3 < N) v.w = deg[base + 3];
    }
    int s = v.x + v.y + v.z + v.w;
    lsum[t] = s;
    __syncthreads();
    for (int d = 1; d < 256; d <<= 1) {
        int val = (t >= d) ? lsum[t - d] : 0;
        __syncthreads();
        lsum[t] += val;
        __syncthreads();
    }
    int run = lsum[t] - s;
    if (t == 255) bsum[blockIdx.x] = lsum[t];
    if (base + 0 < N) { off[base + 0] = run; run += v.x; }
    if (base + 1 < N) { off[base + 1] = run; run += v.y; }
    if (base + 2 < N) { off[base + 2] = run; run += v.z; }
    if (base + 3 < N) { off[base + 3] = run; run += v.w; }
}

__global__ __launch_bounds__(1024) void scan_bsum_kernel(int* bsum, int nb)
{
    __shared__ int l[1024];
    int t = threadIdx.x;
    int v = (t < nb) ? bsum[t] : 0;
    l[t] = v;
    __syncthreads();
    for (int d = 1; d < 1024; d <<= 1) {
        int val = (t >= d) ? l[t - d] : 0;
        __syncthreads();
        l[t] += val;
        __syncthreads();
    }
    if (t < nb) bsum[t] = l[t] - v;
}

__global__ __launch_bounds__(256) void add_off_kernel(
    int* __restrict__ off, const int* __restrict__ bsum,
    int* __restrict__ cursor, int N, int E)
{
    int bo = bsum[blockIdx.x];
    int base = blockIdx.x * 1024 + threadIdx.x * 4;
    #pragma unroll
    for (int j = 0; j < 4; ++j) {
        int i = base + j;
        if (i < N) { int o = off[i] + bo; off[i] = o; cursor[i] = o; }
    }
    if (blockIdx.x == 0 && threadIdx.x == 0) off[N] = E;
}

__global__ __launch_bounds__(256) void init_bcur_kernel(
    const int* __restrict__ off, int* __restrict__ bcur, int N, int NB)
{
    int k = blockIdx.x * 256 + threadIdx.x;
    if (k < NB) {
        int node = k << 8;
        bcur[k] = off[node < N ? node : N];
    }
}

// ---------------------------------------------------------------------------
// Pass A: partition edges into 256-node buckets.
// csr_src entry = src(20b) | dstlow(8b)<<20 ; csr_w entry = bf16(weight).
// ---------------------------------------------------------------------------
__global__ __launch_bounds__(256) void pass_a_kernel(
    const int* __restrict__ src, const int* __restrict__ dst,
    const float* __restrict__ ew, int* __restrict__ bcur,
    int* __restrict__ csr_src, unsigned short* __restrict__ csr_w,
    int E, int NB)
{
    __shared__ int lcnt[MAXNB];
    __shared__ int lcur[MAXNB];
    int nchunks = (E + CHUNK - 1) / CHUNK;
    int t = threadIdx.x;
    for (int c = blockIdx.x; c < nchunks; c += gridDim.x) {
        int base = c * CHUNK;
        int lim = min(CHUNK, E - base);
        for (int k = t; k < NB; k += 256) lcnt[k] = 0;
        __syncthreads();
        for (int j = t; j < lim; j += 256)
            atomicAdd(&lcnt[dst[base + j] >> 8], 1);
        __syncthreads();
        for (int k = t; k < NB; k += 256) {
            int cnt = lcnt[k];
            lcur[k] = cnt > 0 ? atomicAdd(&bcur[k], cnt) : 0;
        }
        __syncthreads();
        for (int j = t; j < lim; j += 256) {
            int e = base + j;
            int dv = dst[e];
            int p = atomicAdd(&lcur[dv >> 8], 1);
            csr_src[p] = (src[e] & 0xFFFFF) | ((dv & 255) << 20);
            csr_w[p]   = f2bf(ew[e]);
        }
        __syncthreads();
    }
}

// ---------------------------------------------------------------------------
// Pass B: per bucket, counting-scatter segment into per-node order via LDS.
// ---------------------------------------------------------------------------
__global__ __launch_bounds__(256) void pass_b_kernel(
    int* __restrict__ csr_src, unsigned short* __restrict__ csr_w,
    const int* __restrict__ off, int* __restrict__ ovf, int N)
{
    __shared__ int ssrc[MAXSEG];
    __shared__ unsigned short sw[MAXSEG];
    __shared__ int lcur[256];
    int k = blockIdx.x;
    int nlo = k << 8;
    int nhi = min(nlo + 256, N);
    int segbeg = off[nlo], segend = off[nhi];
    int len = segend - segbeg;
    int t = threadIdx.x;
    if (t == 0) ovf[k] = (len > MAXSEG) ? 1 : 0;
    if (len > MAXSEG) return;
    if (nlo + t < nhi) lcur[t] = off[nlo + t] - segbeg;
    __syncthreads();
    for (int j = t; j < len; j += 256) {
        int e = csr_src[segbeg + j];
        unsigned short w = csr_w[segbeg + j];
        int slot = (e >> 20) & 255;
        int p = atomicAdd(&lcur[slot], 1);
        ssrc[p] = e & 0xFFFFF;
        sw[p]   = w;
    }
    __syncthreads();
    for (int j = t; j < len; j += 256) {
        csr_src[segbeg + j] = ssrc[j];
        csr_w[segbeg + j]   = sw[j];
    }
}

// Rare fallback for oversized buckets: bounce via tmp (aggb region).
__global__ __launch_bounds__(256) void pass_b_big_kernel(
    int* __restrict__ csr_src, unsigned short* __restrict__ csr_w,
    const int* __restrict__ off, const int* __restrict__ ovf,
    int* __restrict__ gcur, int* __restrict__ tmp_src,
    unsigned short* __restrict__ tmp_w, int N)
{
    int k = blockIdx.x;
    if (!ovf[k]) return;
    int nlo = k << 8;
    int nhi = min(nlo + 256, N);
    int segbeg = off[nlo], segend = off[nhi];
    int len = segend - segbeg;
    int t = threadIdx.x;
    for (int j = t; j < len; j += 256) {
        tmp_src[segbeg + j] = csr_src[segbeg + j];
        tmp_w[segbeg + j]   = csr_w[segbeg + j];
    }
    __syncthreads();
    for (int j = t; j < len; j += 256) {
        int e = tmp_src[segbeg + j];
        int node = nlo + ((e >> 20) & 255);
        int p = atomicAdd(&gcur[node], 1);
        csr_src[p] = e & 0xFFFFF;
        csr_w[p]   = tmp_w[segbeg + j];
    }
}

// ===========================================================================
// feat f32 -> bf16 (one pass)
// ===========================================================================
__global__ __launch_bounds__(256) void feat2bf_kernel(
    const float* __restrict__ feat, unsigned short* __restrict__ featb, long n8)
{
    long i = (long)blockIdx.x * 256 + threadIdx.x;
    long stride = (long)gridDim.x * 256;
    for (; i < n8; i += stride) {
        float4 a = *reinterpret_cast<const float4*>(feat + i * 8);
        float4 b = *reinterpret_cast<const float4*>(feat + i * 8 + 4);
        u16x8 o;
        o[0] = f2bf(a.x); o[1] = f2bf(a.y); o[2] = f2bf(a.z); o[3] = f2bf(a.w);
        o[4] = f2bf(b.x); o[5] = f2bf(b.y); o[6] = f2bf(b.z); o[7] = f2bf(b.w);
        reinterpret_cast<u16x8*>(featb)[i] = o;
    }
}

// ===========================================================================
// Atomic-free aggregation from bf16 feat: 16 lanes/node x 8 bf16/lane.
// ===========================================================================
__global__ __launch_bounds__(256) void gather_agg_kernel(
    const unsigned short* __restrict__ featb, const int* __restrict__ csr_src,
    const unsigned short* __restrict__ csr_w, const int* __restrict__ off,
    unsigned short* __restrict__ aggb, int N)
{
    int g = (int)((blockIdx.x * 256 + threadIdx.x) >> 4);
    if (g >= N) return;
    int q = (threadIdx.x & 15) << 3;
    int beg = off[g], end = off[g + 1];
    float acc[8] = {0.f, 0.f, 0.f, 0.f, 0.f, 0.f, 0.f, 0.f};
    int i = beg;
    for (; i + 2 <= end; i += 2) {
        int s0 = csr_src[i];
        int s1 = csr_src[i + 1];
        float w0 = bf2f(csr_w[i]);
        float w1 = bf2f(csr_w[i + 1]);
        u16x8 v0 = *reinterpret_cast<const u16x8*>(featb + (long)s0 * D + q);
        u16x8 v1 = *reinterpret_cast<const u16x8*>(featb + (long)s1 * D + q);
        #pragma unroll
        for (int j = 0; j < 8; ++j) acc[j] += bf2f(v0[j]) * w0;
        #pragma unroll
        for (int j = 0; j < 8; ++j) acc[j] += bf2f(v1[j]) * w1;
    }
    if (i < end) {
        int s0 = csr_src[i];
        float w0 = bf2f(csr_w[i]);
        u16x8 v0 = *reinterpret_cast<const u16x8*>(featb + (long)s0 * D + q);
        #pragma unroll
        for (int j = 0; j < 8; ++j) acc[j] += bf2f(v0[j]) * w0;
    }
    u16x8 o;
    #pragma unroll
    for (int j = 0; j < 8; ++j) o[j] = f2bf(acc[j]);
    *reinterpret_cast<u16x8*>(aggb + (long)g * D + q) = o;
}

// ===========================================================================
// One-time: W (f32, [k][col]) -> B-fragment-swizzled bf16 buffer.
// ===========================================================================
__global__ __launch_bounds__(256) void prep_w_kernel(
    const float* __restrict__ W, unsigned short* __restrict__ wswz)
{
    int i = blockIdx.x * 256 + threadIdx.x;   // 0..16383
    int j  = i & 7;
    int l  = (i >> 3) & 63;
    int c  = (i >> 9) & 7;
    int ks = i >> 12;
    int k   = ks * 32 + ((l >> 4) * 8) + j;
    int col = c * 16 + (l & 15);
    wswz[i] = f2bf(W[k * D + col]);
}

// ===========================================================================
// MFMA GEMM: h = prelu(agg_bf16 @ W_bf16 + b, a1); h stored bf16 IN PLACE in
// aggb (each block writes only rows it already consumed); col stats.
// NOTE: aggb/houtb alias intentionally -> no __restrict__ on them.
// ===========================================================================
__global__ __launch_bounds__(256) void gemm_stats_mfma_kernel(
    const unsigned short* aggb, const unsigned short* __restrict__ wswz,
    const float* __restrict__ bg, const float* __restrict__ a1p,
    unsigned short* houtb, float* __restrict__ stats, int N)
{
    __shared__ unsigned short Bl[16384];   // 32 KB: fragment-ready W
    __shared__ float sblk[2][D];

    int t = threadIdx.x;
    for (int i = t; i < 2048; i += 256)
        reinterpret_cast<float4*>(Bl)[i] = reinterpret_cast<const float4*>(wswz)[i];
    if (t < D) { sblk[0][t] = 0.f; sblk[1][t] = 0.f; }
    __syncthreads();

    const int lane = t & 63;
    const int wv   = t >> 6;
    const long rbase = (long)blockIdx.x * 128 + wv * 32;
    const int lr = lane & 15;
    const int lk = lane >> 4;

    f32x4 acc[2][8];
    #pragma unroll
    for (int rt = 0; rt < 2; ++rt)
        #pragma unroll
        for (int c = 0; c < 8; ++c)
            acc[rt][c] = (f32x4){0.f, 0.f, 0.f, 0.f};

    long r0 = rbase + lr;
    long r1 = rbase + 16 + lr;
    long r0c = (r0 < N) ? r0 : 0;
    long r1c = (r1 < N) ? r1 : 0;

    #pragma unroll
    for (int ks = 0; ks < 4; ++ks) {
        bf16x8 a0 = *reinterpret_cast<const bf16x8*>(aggb + r0c * D + ks * 32 + lk * 8);
        bf16x8 a1f = *reinterpret_cast<const bf16x8*>(aggb + r1c * D + ks * 32 + lk * 8);
        #pragma unroll
        for (int c = 0; c < 8; ++c) {
            bf16x8 bfr = *reinterpret_cast<const bf16x8*>(&Bl[((ks * 8 + c) * 64 + lane) * 8]);
            acc[0][c] = __builtin_amdgcn_mfma_f32_16x16x32_bf16(a0, bfr, acc[0][c], 0, 0, 0);
            acc[1][c] = __builtin_amdgcn_mfma_f32_16x16x32_bf16(a1f, bfr, acc[1][c], 0, 0, 0);
        }
    }

    const float a1v = a1p[0];
    float bias[8];
    #pragma unroll
    for (int c = 0; c < 8; ++c) bias[c] = bg[c * 16 + lr];

    float csum[8] = {0,0,0,0,0,0,0,0};
    float csq[8]  = {0,0,0,0,0,0,0,0};
    #pragma unroll
    for (int rt = 0; rt < 2; ++rt) {
        #pragma unroll
        for (int reg = 0; reg < 4; ++reg) {
            long row = rbase + rt * 16 + lk * 4 + reg;
            if (row >= N) continue;
            #pragma unroll
            for (int c = 0; c < 8; ++c) {
                float v = acc[rt][c][reg] + bias[c];
                v = v >= 0.f ? v : v * a1v;
                houtb[row * D + c * 16 + lr] = f2bf(v);
                csum[c] += v;
                csq[c]  += v * v;
            }
        }
    }
    #pragma unroll
    for (int c = 0; c < 8; ++c) {
        atomicAdd(&sblk[0][c * 16 + lr], csum[c]);
        atomicAdd(&sblk[1][c * 16 + lr], csq[c]);
    }
    __syncthreads();
    if (t < D) {
        atomicAdd(&stats[t],     sblk[0][t]);
        atomicAdd(&stats[D + t], sblk[1][t]);
    }
}

// ===========================================================================
// Fallback path kernels (ws too small): f32 atomic scatter + f32 GEMM.
// ===========================================================================
__global__ __launch_bounds__(256) void scatter_kernel(
    const float* __restrict__ feat, const int* __restrict__ src,
    const int* __restrict__ dst, const float* __restrict__ ew,
    float* __restrict__ agg, int E)
{
    long tid = (long)blockIdx.x * blockDim.x + threadIdx.x;
    int e = (int)(tid >> 5);
    if (e >= E) return;
    int q = ((int)tid & 31) << 2;
    int s = src[e];
    int d = dst[e];
    float w = ew[e];
    float4 v = *reinterpret_cast<const float4*>(feat + (long)s * D + q);
    float* o = agg + (long)d * D + q;
    atomicAdd(o + 0, v.x * w);
    atomicAdd(o + 1, v.y * w);
    atomicAdd(o + 2, v.z * w);
    atomicAdd(o + 3, v.w * w);
}

__global__ __launch_bounds__(256) void gemm_stats_kernel(
    const float* __restrict__ agg, const float* __restrict__ Wg,
    const float* __restrict__ bg, const float* __restrict__ a1,
    float* __restrict__ hout, float* __restrict__ stats, int N)
{
    __shared__ float Wl[D * D];
    __shared__ float sblk[2][D];

    int t = threadIdx.x;
    for (int i = t; i < D * D / 4; i += 256) {
        reinterpret_cast<float4*>(Wl)[i] =
            reinterpret_cast<const float4*>(Wg)[i];
    }
    if (t < D) { sblk[0][t] = 0.f; sblk[1][t] = 0.f; }
    __syncthreads();

    const int c0 = (t & 31) << 2;
    const int rbase = blockIdx.x * 32 + (t >> 5) * 4;
    const float a1v = a1[0];

    bool valid[4];
    #pragma unroll
    for (int i = 0; i < 4; ++i) valid[i] = (rbase + i) < N;

    float acc[4][4];
    float4 bv = *reinterpret_cast<const float4*>(bg + c0);
    #pragma unroll
    for (int i = 0; i < 4; ++i) {
        acc[i][0] = bv.x; acc[i][1] = bv.y; acc[i][2] = bv.z; acc[i][3] = bv.w;
    }

    for (int k0 = 0; k0 < D; k0 += 4) {
        float4 a[4];
        #pragma unroll
        for (int i = 0; i < 4; ++i) {
            a[i] = valid[i]
                ? *reinterpret_cast<const float4*>(agg + (long)(rbase + i) * D + k0)
                : make_float4(0.f, 0.f, 0.f, 0.f);
        }
        #pragma unroll
        for (int kk = 0; kk < 4; ++kk) {
            float4 wv = *reinterpret_cast<const float4*>(&Wl[(k0 + kk) * D + c0]);
            #pragma unroll
            for (int i = 0; i < 4; ++i) {
                float av = kk == 0 ? a[i].x : kk == 1 ? a[i].y : kk == 2 ? a[i].z : a[i].w;
                acc[i][0] += av * wv.x;
                acc[i][1] += av * wv.y;
                acc[i][2] += av * wv.z;
                acc[i][3] += av * wv.w;
            }
        }
    }

    float csum[4] = {0.f, 0.f, 0.f, 0.f};
    float csq[4]  = {0.f, 0.f, 0.f, 0.f};
    #pragma unroll
    for (int i = 0; i < 4; ++i) {
        if (!valid[i]) continue;
        float4 o;
        #pragma unroll
        for (int j = 0; j < 4; ++j) {
            float v = acc[i][j];
            v = v >= 0.f ? v : v * a1v;
            (&o.x)[j] = v;
            csum[j] += v;
            csq[j]  += v * v;
        }
        *reinterpret_cast<float4*>(hout + (long)(rbase + i) * D + c0) = o;
    }
    #pragma unroll
    for (int j = 0; j < 4; ++j) {
        atomicAdd(&sblk[0][c0 + j], csum[j]);
        atomicAdd(&sblk[1][c0 + j], csq[j]);
    }
    __syncthreads();
    if (t < D) {
        atomicAdd(&stats[t],     sblk[0][t]);
        atomicAdd(&stats[D + t], sblk[1][t]);
    }
}

// ===========================================================================
__global__ void finalize_kernel(const float* __restrict__ stats,
                                const float* __restrict__ gamma,
                                const float* __restrict__ beta,
                                float* __restrict__ ss, int N)
{
    int c = threadIdx.x;
    float invN = 1.0f / (float)N;
    float mean = stats[c] * invN;
    float var  = stats[D + c] * invN - mean * mean;
    float sc = gamma[c] * rsqrtf(var + BN_EPS);
    ss[c]     = sc;
    ss[D + c] = beta[c] - mean * sc;
}

// BN apply + PReLU(a2): bf16 h in, f32 out.
__global__ __launch_bounds__(256) void bn_prelu_bf16_kernel(
    const unsigned short* __restrict__ hb, const float* __restrict__ ss,
    const float* __restrict__ a2, float* __restrict__ out, long n8)
{
    const float a2v = a2[0];
    long i = (long)blockIdx.x * blockDim.x + threadIdx.x;
    long stride = (long)gridDim.x * blockDim.x;
    for (; i < n8; i += stride) {
        u16x8 hv = reinterpret_cast<const u16x8*>(hb)[i];
        int c0 = ((int)i & 15) << 3;
        float4 sc0 = *reinterpret_cast<const float4*>(ss + c0);
        float4 sc1 = *reinterpret_cast<const float4*>(ss + c0 + 4);
        float4 sh0 = *reinterpret_cast<const float4*>(ss + D + c0);
        float4 sh1 = *reinterpret_cast<const float4*>(ss + D + c0 + 4);
        float4 o0, o1;
        float v;
        v = bf2f(hv[0]) * sc0.x + sh0.x; o0.x = v >= 0.f ? v : v * a2v;
        v = bf2f(hv[1]) * sc0.y + sh0.y; o0.y = v >= 0.f ? v : v * a2v;
        v = bf2f(hv[2]) * sc0.z + sh0.z; o0.z = v >= 0.f ? v : v * a2v;
        v = bf2f(hv[3]) * sc0.w + sh0.w; o0.w = v >= 0.f ? v : v * a2v;
        v = bf2f(hv[4]) * sc1.x + sh1.x; o1.x = v >= 0.f ? v : v * a2v;
        v = bf2f(hv[5]) * sc1.y + sh1.y; o1.y = v >= 0.f ? v : v * a2v;
        v = bf2f(hv[6]) * sc1.z + sh1.z; o1.z = v >= 0.f ? v : v * a2v;
        v = bf2f(hv[7]) * sc1.w + sh1.w; o1.w = v >= 0.f ? v : v * a2v;
        *reinterpret_cast<float4*>(out + i * 8)     = o0;
        *reinterpret_cast<float4*>(out + i * 8 + 4) = o1;
    }
}

// f32 variant for the fallback path (in place on d_out).
__global__ __launch_bounds__(256) void bn_prelu_kernel(
    float* __restrict__ h, const float* __restrict__ ss,
    const float* __restrict__ a2, long n4)
{
    const float a2v = a2[0];
    long i = (long)blockIdx.x * blockDim.x + threadIdx.x;
    long stride = (long)gridDim.x * blockDim.x;
    for (; i < n4; i += stride) {
        float4 x = reinterpret_cast<float4*>(h)[i];
        int c0 = ((int)(i & 31)) << 2;
        float4 sc = *reinterpret_cast<const float4*>(ss + c0);
        float4 sh = *reinterpret_cast<const float4*>(ss + D + c0);
        float v;
        v = x.x * sc.x + sh.x; x.x = v >= 0.f ? v : v * a2v;
        v = x.y * sc.y + sh.y; x.y = v >= 0.f ? v : v * a2v;
        v = x.z * sc.z + sh.z; x.z = v >= 0.f ? v : v * a2v;
        v = x.w * sc.w + sh.w; x.w = v >= 0.f ? v : v * a2v;
        reinterpret_cast<float4*>(h)[i] = x;
    }
}

// ===========================================================================
extern "C" void kernel_launch(void* const* d_in, const int* in_sizes, int n_in,
                              void* d_out, int out_size, void* d_ws, size_t ws_size,
                              hipStream_t stream)
{
    const float* feat  = (const float*)d_in[0];
    const int*   src   = (const int*)d_in[1];
    const int*   dst   = (const int*)d_in[2];
    const float* ew    = (const float*)d_in[3];
    const float* W     = (const float*)d_in[4];
    const float* b     = (const float*)d_in[5];
    const float* a1    = (const float*)d_in[6];
    const float* gamma = (const float*)d_in[7];
    const float* beta  = (const float*)d_in[8];
    const float* a2    = (const float*)d_in[9];

    const int N = in_sizes[0] / D;
    const int E = in_sizes[1];

    // ws layout (16B-aligned chunks)
    char* p = (char*)d_ws;
    unsigned short* featb = (unsigned short*)p; p += (size_t)N * D * sizeof(unsigned short);
    unsigned short* aggb  = (unsigned short*)p; p += (size_t)N * D * sizeof(unsigned short);
    int* csr_src = (int*)p;               p += (size_t)E * sizeof(int);
    unsigned short* csr_w = (unsigned short*)p; p += (size_t)((E + 7) & ~7) * sizeof(unsigned short);
    int*   deg = (int*)p;                 p += (size_t)((N + 3) & ~3) * sizeof(int);   // gcur
    int*   off = (int*)p;                 p += (size_t)((N + 5) & ~3) * sizeof(int);
    int*   bsum = (int*)p;                p += 1024 * sizeof(int);
    int*   bcur = (int*)p;                p += MAXNB * sizeof(int);
    int*   ovf  = (int*)p;                p += MAXNB * sizeof(int);
    unsigned short* wswz = (unsigned short*)p; p += 16384 * sizeof(unsigned short);
    float* stats = (float*)p;             p += 2 * D * sizeof(float);
    float* ss    = (float*)p;             p += 2 * D * sizeof(float);
    size_t need = (size_t)(p - (char*)d_ws);
    float* out = (float*)d_out;

    int nb = (N + 1023) / 1024;           // scan level-1 blocks
    int NB = (N + 255) / 256;             // partition buckets

    if (ws_size >= need && nb <= 1024) {
        // ---- CSR + bf16 + MFMA path ----
        hipMemsetAsync(deg, 0, (size_t)N * sizeof(int), stream);
        hipMemsetAsync(stats, 0, 2 * D * sizeof(float), stream);
        hist_kernel<<<2048, 256, 0, stream>>>(dst, deg, E);
        scan_block_kernel<<<nb, 256, 0, stream>>>(deg, off, bsum, N);
        scan_bsum_kernel<<<1, 1024, 0, stream>>>(bsum, nb);
        add_off_kernel<<<nb, 256, 0, stream>>>(off, bsum, deg, N, E);
        init_bcur_kernel<<<(NB + 255) / 256, 256, 0, stream>>>(off, bcur, N, NB);
        int nchunks = (E + CHUNK - 1) / CHUNK;
        pass_a_kernel<<<min(nchunks, 1024), 256, 0, stream>>>(src, dst, ew, bcur, csr_src, csr_w, E, NB);
        pass_b_kernel<<<NB, 256, 0, stream>>>(csr_src, csr_w, off, ovf, N);
        pass_b_big_kernel<<<NB, 256, 0, stream>>>(csr_src, csr_w, off, ovf, deg,
                                                  (int*)aggb, (unsigned short*)((int*)aggb + E), N);
        long n8 = (long)N * D / 8;
        feat2bf_kernel<<<2048, 256, 0, stream>>>(feat, featb, n8);
        int ablocks = (int)(((long)N * 16 + 255) / 256);
        gather_agg_kernel<<<ablocks, 256, 0, stream>>>(featb, csr_src, csr_w, off, aggb, N);
        prep_w_kernel<<<64, 256, 0, stream>>>(W, wswz);
        int gblocks = (N + 127) / 128;
        gemm_stats_mfma_kernel<<<gblocks, 256, 0, stream>>>(aggb, wswz, b, a1, aggb, stats, N);
        finalize_kernel<<<1, D, 0, stream>>>(stats, gamma, beta, ss, N);
        bn_prelu_bf16_kernel<<<2048, 256, 0, stream>>>(aggb, ss, a2, out, n8);
    } else {
        // ---- fallback: f32 atomic scatter + f32 GEMM ----
        float* agg = (float*)d_ws;
        stats = agg + (size_t)N * D;
        ss    = stats + 2 * D;
        hipMemsetAsync(agg, 0, ((size_t)N * D + 2 * D) * sizeof(float), stream);
        long nthreads = (long)E * 32;
        int sblocks = (int)((nthreads + 255) / 256);
        scatter_kernel<<<sblocks, 256, 0, stream>>>(feat, src, dst, ew, agg, E);
        int gblocks = (N + 31) / 32;
        gemm_stats_kernel<<<gblocks, 256, 0, stream>>>(agg, W, b, a1, out, stats, N);
        finalize_kernel<<<1, D, 0, stream>>>(stats, gamma, beta, ss, N);
        long n4 = (long)N * D / 4;
        bn_prelu_kernel<<<2048, 256, 0, stream>>>(out, ss, a2, n4);
    }
}

// Round 7
// 224.653 us; speedup vs baseline: 12.9225x; 1.2377x over previous
//
#include <hip/hip_runtime.h>

#define D 128
#define BN_EPS 1e-5f
#define CHUNK 8192
#define MAXSEG 6144
#define MAXNB 4096

typedef __attribute__((ext_vector_type(8))) short bf16x8;
typedef __attribute__((ext_vector_type(8))) unsigned short u16x8;
typedef __attribute__((ext_vector_type(4))) float f32x4;

__device__ __forceinline__ unsigned short f2bf(float f) {
    unsigned int u = __float_as_uint(f);
    u += 0x7FFFu + ((u >> 16) & 1u);
    return (unsigned short)(u >> 16);
}
__device__ __forceinline__ float bf2f(unsigned short u) {
    return __uint_as_float(((unsigned int)u) << 16);
}

// ===========================================================================
// Bucket-level histogram in LDS (NB = #256-node buckets, <= MAXNB).
// ===========================================================================
__global__ __launch_bounds__(256) void bucket_hist_kernel(
    const int* __restrict__ dst, int* __restrict__ bhist, int E, int NB)
{
    __shared__ int lcnt[MAXNB];
    int t = threadIdx.x;
    for (int k = t; k < NB; k += 256) lcnt[k] = 0;
    __syncthreads();
    int i = blockIdx.x * 256 + t;
    int stride = gridDim.x * 256;
    for (; i < E; i += stride) atomicAdd(&lcnt[dst[i] >> 8], 1);
    __syncthreads();
    for (int k = t; k < NB; k += 256) {
        int c = lcnt[k];
        if (c) atomicAdd(&bhist[k], c);
    }
}

// Single-block exclusive scan of NB (<=4096) bucket counts -> bseg, bcur.
__global__ __launch_bounds__(1024) void bucket_scan_kernel(
    const int* __restrict__ bhist, int* __restrict__ bseg,
    int* __restrict__ bcur, int* __restrict__ off, int NB, int N, int E)
{
    __shared__ int part[1024];
    int t = threadIdx.x;
    int base = t * 4;
    int4 v = make_int4(0, 0, 0, 0);
    if (base + 3 < NB) {
        v = *reinterpret_cast<const int4*>(bhist + base);
    } else {
        if (base + 0 < NB) v.x = bhist[base + 0];
        if (base + 1 < NB) v.y = bhist[base + 1];
        if (base + 2 < NB) v.z = bhist[base + 2];
        if (base + 3 < NB) v.w = bhist[base + 3];
    }
    int s = v.x + v.y + v.z + v.w;
    part[t] = s;
    __syncthreads();
    for (int d = 1; d < 1024; d <<= 1) {
        int val = (t >= d) ? part[t - d] : 0;
        __syncthreads();
        part[t] += val;
        __syncthreads();
    }
    int run = part[t] - s;
    if (base + 0 < NB) { bseg[base + 0] = run; bcur[base + 0] = run; run += v.x; }
    if (base + 1 < NB) { bseg[base + 1] = run; bcur[base + 1] = run; run += v.y; }
    if (base + 2 < NB) { bseg[base + 2] = run; bcur[base + 2] = run; run += v.z; }
    if (base + 3 < NB) { bseg[base + 3] = run; bcur[base + 3] = run; run += v.w; }
    if (t == 1023) { bseg[NB] = E; off[N] = E; }
}

// ---------------------------------------------------------------------------
// Pass A: partition edges into 256-node buckets.
// csr_src entry = src(20b) | dstlow(8b)<<20 ; csr_w entry = bf16(weight).
// ---------------------------------------------------------------------------
__global__ __launch_bounds__(256) void pass_a_kernel(
    const int* __restrict__ src, const int* __restrict__ dst,
    const float* __restrict__ ew, int* __restrict__ bcur,
    int* __restrict__ csr_src, unsigned short* __restrict__ csr_w,
    int E, int NB)
{
    __shared__ int lcnt[MAXNB];
    __shared__ int lcur[MAXNB];
    int nchunks = (E + CHUNK - 1) / CHUNK;
    int t = threadIdx.x;
    for (int c = blockIdx.x; c < nchunks; c += gridDim.x) {
        int base = c * CHUNK;
        int lim = min(CHUNK, E - base);
        for (int k = t; k < NB; k += 256) lcnt[k] = 0;
        __syncthreads();
        for (int j = t; j < lim; j += 256)
            atomicAdd(&lcnt[dst[base + j] >> 8], 1);
        __syncthreads();
        for (int k = t; k < NB; k += 256) {
            int cnt = lcnt[k];
            lcur[k] = cnt > 0 ? atomicAdd(&bcur[k], cnt) : 0;
        }
        __syncthreads();
        for (int j = t; j < lim; j += 256) {
            int e = base + j;
            int dv = dst[e];
            int p = atomicAdd(&lcur[dv >> 8], 1);
            csr_src[p] = (src[e] & 0xFFFFF) | ((dv & 255) << 20);
            csr_w[p]   = f2bf(ew[e]);
        }
        __syncthreads();
    }
}

// ---------------------------------------------------------------------------
// Pass B: per bucket — LDS per-node count from packed dst bits, LDS scan,
// write off[] (coalesced), counting-scatter segment into per-node order.
// ---------------------------------------------------------------------------
__global__ __launch_bounds__(256) void pass_b_kernel(
    int* csr_src, unsigned short* csr_w,
    const int* __restrict__ bseg, int* __restrict__ off,
    int* __restrict__ gcur, int* __restrict__ ovf, int N)
{
    __shared__ int ssrc[MAXSEG];
    __shared__ unsigned short sw[MAXSEG];
    __shared__ int cnt[256];
    __shared__ int pref[256];
    int k = blockIdx.x;
    int nlo = k << 8;
    int nhi = min(nlo + 256, N);
    int segbeg = bseg[k], segend = bseg[k + 1];
    int len = segend - segbeg;
    int t = threadIdx.x;
    cnt[t] = 0;
    __syncthreads();
    // phase 1: per-node counts from packed dst-low bits
    for (int j = t; j < len; j += 256)
        atomicAdd(&cnt[(csr_src[segbeg + j] >> 20) & 255], 1);
    __syncthreads();
    // exclusive scan of the 256 counts
    int s = cnt[t];
    pref[t] = s;
    __syncthreads();
    for (int d = 1; d < 256; d <<= 1) {
        int val = (t >= d) ? pref[t - d] : 0;
        __syncthreads();
        pref[t] += val;
        __syncthreads();
    }
    int excl = pref[t] - s;
    if (nlo + t < nhi) off[nlo + t] = segbeg + excl;
    bool big = len > MAXSEG;
    if (t == 0) ovf[k] = big ? 1 : 0;
    if (big) {
        if (nlo + t < nhi) gcur[nlo + t] = segbeg + excl;
        return;
    }
    // reuse cnt[] as scatter cursors
    __syncthreads();
    cnt[t] = excl;
    __syncthreads();
    // phase 2: scatter into LDS in per-node order
    for (int j = t; j < len; j += 256) {
        int e = csr_src[segbeg + j];
        int slot = (e >> 20) & 255;
        int p = atomicAdd(&cnt[slot], 1);
        ssrc[p] = e & 0xFFFFF;
        sw[p]   = csr_w[segbeg + j];
    }
    __syncthreads();
    for (int j = t; j < len; j += 256) {
        csr_src[segbeg + j] = ssrc[j];
        csr_w[segbeg + j]   = sw[j];
    }
}

// Rare fallback for oversized buckets: bounce via tmp (aggb region).
__global__ __launch_bounds__(256) void pass_b_big_kernel(
    int* __restrict__ csr_src, unsigned short* __restrict__ csr_w,
    const int* __restrict__ off, const int* __restrict__ ovf,
    int* __restrict__ gcur, int* __restrict__ tmp_src,
    unsigned short* __restrict__ tmp_w, int N)
{
    int k = blockIdx.x;
    if (!ovf[k]) return;
    int nlo = k << 8;
    int nhi = min(nlo + 256, N);
    int segbeg = off[nlo], segend = (nhi < N) ? off[nhi] : off[N];
    int len = segend - segbeg;
    int t = threadIdx.x;
    for (int j = t; j < len; j += 256) {
        tmp_src[segbeg + j] = csr_src[segbeg + j];
        tmp_w[segbeg + j]   = csr_w[segbeg + j];
    }
    __syncthreads();
    for (int j = t; j < len; j += 256) {
        int e = tmp_src[segbeg + j];
        int node = nlo + ((e >> 20) & 255);
        int p = atomicAdd(&gcur[node], 1);
        csr_src[p] = e & 0xFFFFF;
        csr_w[p]   = tmp_w[segbeg + j];
    }
}

// ===========================================================================
// feat f32 -> bf16 (one pass)
// ===========================================================================
__global__ __launch_bounds__(256) void feat2bf_kernel(
    const float* __restrict__ feat, unsigned short* __restrict__ featb, long n8)
{
    long i = (long)blockIdx.x * 256 + threadIdx.x;
    long stride = (long)gridDim.x * 256;
    for (; i < n8; i += stride) {
        float4 a = *reinterpret_cast<const float4*>(feat + i * 8);
        float4 b = *reinterpret_cast<const float4*>(feat + i * 8 + 4);
        u16x8 o;
        o[0] = f2bf(a.x); o[1] = f2bf(a.y); o[2] = f2bf(a.z); o[3] = f2bf(a.w);
        o[4] = f2bf(b.x); o[5] = f2bf(b.y); o[6] = f2bf(b.z); o[7] = f2bf(b.w);
        reinterpret_cast<u16x8*>(featb)[i] = o;
    }
}

// ===========================================================================
// Atomic-free aggregation from bf16 feat: 16 lanes/node x 8 bf16/lane.
// ===========================================================================
__global__ __launch_bounds__(256) void gather_agg_kernel(
    const unsigned short* __restrict__ featb, const int* __restrict__ csr_src,
    const unsigned short* __restrict__ csr_w, const int* __restrict__ off,
    unsigned short* __restrict__ aggb, int N)
{
    int g = (int)((blockIdx.x * 256 + threadIdx.x) >> 4);
    if (g >= N) return;
    int q = (threadIdx.x & 15) << 3;
    int beg = off[g], end = off[g + 1];
    float acc[8] = {0.f, 0.f, 0.f, 0.f, 0.f, 0.f, 0.f, 0.f};
    int i = beg;
    for (; i + 2 <= end; i += 2) {
        int s0 = csr_src[i];
        int s1 = csr_src[i + 1];
        float w0 = bf2f(csr_w[i]);
        float w1 = bf2f(csr_w[i + 1]);
        u16x8 v0 = *reinterpret_cast<const u16x8*>(featb + (long)s0 * D + q);
        u16x8 v1 = *reinterpret_cast<const u16x8*>(featb + (long)s1 * D + q);
        #pragma unroll
        for (int j = 0; j < 8; ++j) acc[j] += bf2f(v0[j]) * w0;
        #pragma unroll
        for (int j = 0; j < 8; ++j) acc[j] += bf2f(v1[j]) * w1;
    }
    if (i < end) {
        int s0 = csr_src[i];
        float w0 = bf2f(csr_w[i]);
        u16x8 v0 = *reinterpret_cast<const u16x8*>(featb + (long)s0 * D + q);
        #pragma unroll
        for (int j = 0; j < 8; ++j) acc[j] += bf2f(v0[j]) * w0;
    }
    u16x8 o;
    #pragma unroll
    for (int j = 0; j < 8; ++j) o[j] = f2bf(acc[j]);
    *reinterpret_cast<u16x8*>(aggb + (long)g * D + q) = o;
}

// ===========================================================================
// One-time: W (f32, [k][col]) -> B-fragment-swizzled bf16 buffer.
// ===========================================================================
__global__ __launch_bounds__(256) void prep_w_kernel(
    const float* __restrict__ W, unsigned short* __restrict__ wswz)
{
    int i = blockIdx.x * 256 + threadIdx.x;   // 0..16383
    int j  = i & 7;
    int l  = (i >> 3) & 63;
    int c  = (i >> 9) & 7;
    int ks = i >> 12;
    int k   = ks * 32 + ((l >> 4) * 8) + j;
    int col = c * 16 + (l & 15);
    wswz[i] = f2bf(W[k * D + col]);
}

// ===========================================================================
// MFMA GEMM: h = prelu(agg_bf16 @ W_bf16 + b, a1); h stored bf16 IN PLACE in
// aggb (each block writes only rows it already consumed); col stats.
// ===========================================================================
__global__ __launch_bounds__(256) void gemm_stats_mfma_kernel(
    const unsigned short* aggb, const unsigned short* __restrict__ wswz,
    const float* __restrict__ bg, const float* __restrict__ a1p,
    unsigned short* houtb, float* __restrict__ stats, int N)
{
    __shared__ unsigned short Bl[16384];   // 32 KB: fragment-ready W
    __shared__ float sblk[2][D];

    int t = threadIdx.x;
    for (int i = t; i < 2048; i += 256)
        reinterpret_cast<float4*>(Bl)[i] = reinterpret_cast<const float4*>(wswz)[i];
    if (t < D) { sblk[0][t] = 0.f; sblk[1][t] = 0.f; }
    __syncthreads();

    const int lane = t & 63;
    const int wv   = t >> 6;
    const long rbase = (long)blockIdx.x * 128 + wv * 32;
    const int lr = lane & 15;
    const int lk = lane >> 4;

    f32x4 acc[2][8];
    #pragma unroll
    for (int rt = 0; rt < 2; ++rt)
        #pragma unroll
        for (int c = 0; c < 8; ++c)
            acc[rt][c] = (f32x4){0.f, 0.f, 0.f, 0.f};

    long r0 = rbase + lr;
    long r1 = rbase + 16 + lr;
    long r0c = (r0 < N) ? r0 : 0;
    long r1c = (r1 < N) ? r1 : 0;

    #pragma unroll
    for (int ks = 0; ks < 4; ++ks) {
        bf16x8 a0 = *reinterpret_cast<const bf16x8*>(aggb + r0c * D + ks * 32 + lk * 8);
        bf16x8 a1f = *reinterpret_cast<const bf16x8*>(aggb + r1c * D + ks * 32 + lk * 8);
        #pragma unroll
        for (int c = 0; c < 8; ++c) {
            bf16x8 bfr = *reinterpret_cast<const bf16x8*>(&Bl[((ks * 8 + c) * 64 + lane) * 8]);
            acc[0][c] = __builtin_amdgcn_mfma_f32_16x16x32_bf16(a0, bfr, acc[0][c], 0, 0, 0);
            acc[1][c] = __builtin_amdgcn_mfma_f32_16x16x32_bf16(a1f, bfr, acc[1][c], 0, 0, 0);
        }
    }

    const float a1v = a1p[0];
    float bias[8];
    #pragma unroll
    for (int c = 0; c < 8; ++c) bias[c] = bg[c * 16 + lr];

    float csum[8] = {0,0,0,0,0,0,0,0};
    float csq[8]  = {0,0,0,0,0,0,0,0};
    #pragma unroll
    for (int rt = 0; rt < 2; ++rt) {
        #pragma unroll
        for (int reg = 0; reg < 4; ++reg) {
            long row = rbase + rt * 16 + lk * 4 + reg;
            if (row >= N) continue;
            #pragma unroll
            for (int c = 0; c < 8; ++c) {
                float v = acc[rt][c][reg] + bias[c];
                v = v >= 0.f ? v : v * a1v;
                houtb[row * D + c * 16 + lr] = f2bf(v);
                csum[c] += v;
                csq[c]  += v * v;
            }
        }
    }
    #pragma unroll
    for (int c = 0; c < 8; ++c) {
        atomicAdd(&sblk[0][c * 16 + lr], csum[c]);
        atomicAdd(&sblk[1][c * 16 + lr], csq[c]);
    }
    __syncthreads();
    if (t < D) {
        atomicAdd(&stats[t],     sblk[0][t]);
        atomicAdd(&stats[D + t], sblk[1][t]);
    }
}

// ===========================================================================
// Fallback path kernels (ws too small): f32 atomic scatter + f32 GEMM.
// ===========================================================================
__global__ __launch_bounds__(256) void scatter_kernel(
    const float* __restrict__ feat, const int* __restrict__ src,
    const int* __restrict__ dst, const float* __restrict__ ew,
    float* __restrict__ agg, int E)
{
    long tid = (long)blockIdx.x * blockDim.x + threadIdx.x;
    int e = (int)(tid >> 5);
    if (e >= E) return;
    int q = ((int)tid & 31) << 2;
    int s = src[e];
    int d = dst[e];
    float w = ew[e];
    float4 v = *reinterpret_cast<const float4*>(feat + (long)s * D + q);
    float* o = agg + (long)d * D + q;
    atomicAdd(o + 0, v.x * w);
    atomicAdd(o + 1, v.y * w);
    atomicAdd(o + 2, v.z * w);
    atomicAdd(o + 3, v.w * w);
}

__global__ __launch_bounds__(256) void gemm_stats_kernel(
    const float* __restrict__ agg, const float* __restrict__ Wg,
    const float* __restrict__ bg, const float* __restrict__ a1,
    float* __restrict__ hout, float* __restrict__ stats, int N)
{
    __shared__ float Wl[D * D];
    __shared__ float sblk[2][D];

    int t = threadIdx.x;
    for (int i = t; i < D * D / 4; i += 256) {
        reinterpret_cast<float4*>(Wl)[i] =
            reinterpret_cast<const float4*>(Wg)[i];
    }
    if (t < D) { sblk[0][t] = 0.f; sblk[1][t] = 0.f; }
    __syncthreads();

    const int c0 = (t & 31) << 2;
    const int rbase = blockIdx.x * 32 + (t >> 5) * 4;
    const float a1v = a1[0];

    bool valid[4];
    #pragma unroll
    for (int i = 0; i < 4; ++i) valid[i] = (rbase + i) < N;

    float acc[4][4];
    float4 bv = *reinterpret_cast<const float4*>(bg + c0);
    #pragma unroll
    for (int i = 0; i < 4; ++i) {
        acc[i][0] = bv.x; acc[i][1] = bv.y; acc[i][2] = bv.z; acc[i][3] = bv.w;
    }

    for (int k0 = 0; k0 < D; k0 += 4) {
        float4 a[4];
        #pragma unroll
        for (int i = 0; i < 4; ++i) {
            a[i] = valid[i]
                ? *reinterpret_cast<const float4*>(agg + (long)(rbase + i) * D + k0)
                : make_float4(0.f, 0.f, 0.f, 0.f);
        }
        #pragma unroll
        for (int kk = 0; kk < 4; ++kk) {
            float4 wv = *reinterpret_cast<const float4*>(&Wl[(k0 + kk) * D + c0]);
            #pragma unroll
            for (int i = 0; i < 4; ++i) {
                float av = kk == 0 ? a[i].x : kk == 1 ? a[i].y : kk == 2 ? a[i].z : a[i].w;
                acc[i][0] += av * wv.x;
                acc[i][1] += av * wv.y;
                acc[i][2] += av * wv.z;
                acc[i][3] += av * wv.w;
            }
        }
    }

    float csum[4] = {0.f, 0.f, 0.f, 0.f};
    float csq[4]  = {0.f, 0.f, 0.f, 0.f};
    #pragma unroll
    for (int i = 0; i < 4; ++i) {
        if (!valid[i]) continue;
        float4 o;
        #pragma unroll
        for (int j = 0; j < 4; ++j) {
            float v = acc[i][j];
            v = v >= 0.f ? v : v * a1v;
            (&o.x)[j] = v;
            csum[j] += v;
            csq[j]  += v * v;
        }
        *reinterpret_cast<float4*>(hout + (long)(rbase + i) * D + c0) = o;
    }
    #pragma unroll
    for (int j = 0; j < 4; ++j) {
        atomicAdd(&sblk[0][c0 + j], csum[j]);
        atomicAdd(&sblk[1][c0 + j], csq[j]);
    }
    __syncthreads();
    if (t < D) {
        atomicAdd(&stats[t],     sblk[0][t]);
        atomicAdd(&stats[D + t], sblk[1][t]);
    }
}

// ===========================================================================
__global__ void finalize_kernel(const float* __restrict__ stats,
                                const float* __restrict__ gamma,
                                const float* __restrict__ beta,
                                float* __restrict__ ss, int N)
{
    int c = threadIdx.x;
    float invN = 1.0f / (float)N;
    float mean = stats[c] * invN;
    float var  = stats[D + c] * invN - mean * mean;
    float sc = gamma[c] * rsqrtf(var + BN_EPS);
    ss[c]     = sc;
    ss[D + c] = beta[c] - mean * sc;
}

// BN apply + PReLU(a2): bf16 h in, f32 out.
__global__ __launch_bounds__(256) void bn_prelu_bf16_kernel(
    const unsigned short* __restrict__ hb, const float* __restrict__ ss,
    const float* __restrict__ a2, float* __restrict__ out, long n8)
{
    const float a2v = a2[0];
    long i = (long)blockIdx.x * blockDim.x + threadIdx.x;
    long stride = (long)gridDim.x * blockDim.x;
    for (; i < n8; i += stride) {
        u16x8 hv = reinterpret_cast<const u16x8*>(hb)[i];
        int c0 = ((int)i & 15) << 3;
        float4 sc0 = *reinterpret_cast<const float4*>(ss + c0);
        float4 sc1 = *reinterpret_cast<const float4*>(ss + c0 + 4);
        float4 sh0 = *reinterpret_cast<const float4*>(ss + D + c0);
        float4 sh1 = *reinterpret_cast<const float4*>(ss + D + c0 + 4);
        float4 o0, o1;
        float v;
        v = bf2f(hv[0]) * sc0.x + sh0.x; o0.x = v >= 0.f ? v : v * a2v;
        v = bf2f(hv[1]) * sc0.y + sh0.y; o0.y = v >= 0.f ? v : v * a2v;
        v = bf2f(hv[2]) * sc0.z + sh0.z; o0.z = v >= 0.f ? v : v * a2v;
        v = bf2f(hv[3]) * sc0.w + sh0.w; o0.w = v >= 0.f ? v : v * a2v;
        v = bf2f(hv[4]) * sc1.x + sh1.x; o1.x = v >= 0.f ? v : v * a2v;
        v = bf2f(hv[5]) * sc1.y + sh1.y; o1.y = v >= 0.f ? v : v * a2v;
        v = bf2f(hv[6]) * sc1.z + sh1.z; o1.z = v >= 0.f ? v : v * a2v;
        v = bf2f(hv[7]) * sc1.w + sh1.w; o1.w = v >= 0.f ? v : v * a2v;
        *reinterpret_cast<float4*>(out + i * 8)     = o0;
        *reinterpret_cast<float4*>(out + i * 8 + 4) = o1;
    }
}

// f32 variant for the fallback path (in place on d_out).
__global__ __launch_bounds__(256) void bn_prelu_kernel(
    float* __restrict__ h, const float* __restrict__ ss,
    const float* __restrict__ a2, long n4)
{
    const float a2v = a2[0];
    long i = (long)blockIdx.x * blockDim.x + threadIdx.x;
    long stride = (long)gridDim.x * blockDim.x;
    for (; i < n4; i += stride) {
        float4 x = reinterpret_cast<float4*>(h)[i];
        int c0 = ((int)(i & 31)) << 2;
        float4 sc = *reinterpret_cast<const float4*>(ss + c0);
        float4 sh = *reinterpret_cast<const float4*>(ss + D + c0);
        float v;
        v = x.x * sc.x + sh.x; x.x = v >= 0.f ? v : v * a2v;
        v = x.y * sc.y + sh.y; x.y = v >= 0.f ? v : v * a2v;
        v = x.z * sc.z + sh.z; x.z = v >= 0.f ? v : v * a2v;
        v = x.w * sc.w + sh.w; x.w = v >= 0.f ? v : v * a2v;
        reinterpret_cast<float4*>(h)[i] = x;
    }
}

// ===========================================================================
extern "C" void kernel_launch(void* const* d_in, const int* in_sizes, int n_in,
                              void* d_out, int out_size, void* d_ws, size_t ws_size,
                              hipStream_t stream)
{
    const float* feat  = (const float*)d_in[0];
    const int*   src   = (const int*)d_in[1];
    const int*   dst   = (const int*)d_in[2];
    const float* ew    = (const float*)d_in[3];
    const float* W     = (const float*)d_in[4];
    const float* b     = (const float*)d_in[5];
    const float* a1    = (const float*)d_in[6];
    const float* gamma = (const float*)d_in[7];
    const float* beta  = (const float*)d_in[8];
    const float* a2    = (const float*)d_in[9];

    const int N = in_sizes[0] / D;
    const int E = in_sizes[1];

    // ws layout (16B-aligned chunks)
    char* p = (char*)d_ws;
    unsigned short* featb = (unsigned short*)p; p += (size_t)N * D * sizeof(unsigned short);
    unsigned short* aggb  = (unsigned short*)p; p += (size_t)N * D * sizeof(unsigned short);
    int* csr_src = (int*)p;               p += (size_t)E * sizeof(int);
    unsigned short* csr_w = (unsigned short*)p; p += (size_t)((E + 7) & ~7) * sizeof(unsigned short);
    int*   gcur = (int*)p;                p += (size_t)((N + 3) & ~3) * sizeof(int);
    int*   off = (int*)p;                 p += (size_t)((N + 5) & ~3) * sizeof(int);
    int*   bseg = (int*)p;                p += (MAXNB + 4) * sizeof(int);
    int*   bcur = (int*)p;                p += MAXNB * sizeof(int);
    int*   ovf  = (int*)p;                p += MAXNB * sizeof(int);
    int*   bhist = (int*)p;               p += MAXNB * sizeof(int);
    float* stats = (float*)p;             p += 2 * D * sizeof(float);
    unsigned short* wswz = (unsigned short*)p; p += 16384 * sizeof(unsigned short);
    float* ss    = (float*)p;             p += 2 * D * sizeof(float);
    size_t need = (size_t)(p - (char*)d_ws);
    float* out = (float*)d_out;

    int NB = (N + 255) / 256;             // partition buckets

    if (ws_size >= need && NB <= MAXNB) {
        // ---- CSR + bf16 + MFMA path ----
        // one memset covers bhist + stats (contiguous)
        hipMemsetAsync(bhist, 0, MAXNB * sizeof(int) + 2 * D * sizeof(float), stream);
        bucket_hist_kernel<<<256, 256, 0, stream>>>(dst, bhist, E, NB);
        bucket_scan_kernel<<<1, 1024, 0, stream>>>(bhist, bseg, bcur, off, NB, N, E);
        int nchunks = (E + CHUNK - 1) / CHUNK;
        pass_a_kernel<<<min(nchunks, 1024), 256, 0, stream>>>(src, dst, ew, bcur, csr_src, csr_w, E, NB);
        pass_b_kernel<<<NB, 256, 0, stream>>>(csr_src, csr_w, bseg, off, gcur, ovf, N);
        pass_b_big_kernel<<<NB, 256, 0, stream>>>(csr_src, csr_w, off, ovf, gcur,
                                                  (int*)aggb, (unsigned short*)((int*)aggb + E), N);
        long n8 = (long)N * D / 8;
        feat2bf_kernel<<<2048, 256, 0, stream>>>(feat, featb, n8);
        int ablocks = (int)(((long)N * 16 + 255) / 256);
        gather_agg_kernel<<<ablocks, 256, 0, stream>>>(featb, csr_src, csr_w, off, aggb, N);
        prep_w_kernel<<<64, 256, 0, stream>>>(W, wswz);
        int gblocks = (N + 127) / 128;
        gemm_stats_mfma_kernel<<<gblocks, 256, 0, stream>>>(aggb, wswz, b, a1, aggb, stats, N);
        finalize_kernel<<<1, D, 0, stream>>>(stats, gamma, beta, ss, N);
        bn_prelu_bf16_kernel<<<2048, 256, 0, stream>>>(aggb, ss, a2, out, n8);
    } else {
        // ---- fallback: f32 atomic scatter + f32 GEMM ----
        float* agg = (float*)d_ws;
        stats = agg + (size_t)N * D;
        ss    = stats + 2 * D;
        hipMemsetAsync(agg, 0, ((size_t)N * D + 2 * D) * sizeof(float), stream);
        long nthreads = (long)E * 32;
        int sblocks = (int)((nthreads + 255) / 256);
        scatter_kernel<<<sblocks, 256, 0, stream>>>(feat, src, dst, ew, agg, E);
        int gblocks = (N + 31) / 32;
        gemm_stats_kernel<<<gblocks, 256, 0, stream>>>(agg, W, b, a1, out, stats, N);
        finalize_kernel<<<1, D, 0, stream>>>(stats, gamma, beta, ss, N);
        long n4 = (long)N * D / 4;
        bn_prelu_kernel<<<2048, 256, 0, stream>>>(out, ss, a2, n4);
    }
}